// Round 1
// 2305.771 us; speedup vs baseline: 1.1234x; 1.1234x over previous
//
#include <hip/hip_runtime.h>
#include <hip/hip_bf16.h>

// Problem constants
#define Bx 32
#define Nx 512
#define Dx 512
#define Hx 8
#define DKx 64
#define FFx 2048
#define TOK (Bx * Nx)          // 16384 tokens
#define EPSx 1e-5f

typedef __bf16 bfrag8 __attribute__((ext_vector_type(8)));
typedef float  f32x4  __attribute__((ext_vector_type(4)));
typedef _Float16 hfrag8 __attribute__((ext_vector_type(8)));
typedef _Float16 h4     __attribute__((ext_vector_type(4)));

struct bf2 { __bf16 hi, lo; };
__device__ __forceinline__ bf2 split2(float v) {
    __bf16 h = (__bf16)v;
    bf2 r; r.hi = h; r.lo = (__bf16)(v - (float)h);
    return r;
}

// ---------------------------------------------------------------------------
__device__ __forceinline__ float ldsel(const void* p32, const void* p16, size_t i, int f32) {
    return f32 ? ((const float*)p32)[i]
               : __bfloat162float(((const __hip_bfloat16*)p16)[i]);
}

__global__ void detect_kernel(const void* __restrict__ x, int* __restrict__ flag)
{
    if (threadIdx.x == 0 && blockIdx.x == 0) {
        const unsigned short* u = (const unsigned short*)x;
        int hits = 0;
        for (int i = 0; i < 256; ++i) {
            int e = (u[i] >> 7) & 0xFF;
            if (e >= 0x86) ++hits;
        }
        *flag = (hits > 8) ? 1 : 0;
    }
}

// ---------------------------------------------------------------------------
__global__ __launch_bounds__(256) void embed_kernel(
    const void* __restrict__ x, const void* __restrict__ We,
    const void* __restrict__ be, float* __restrict__ h, const int* __restrict__ dtp)
{
    const int f32 = *dtp;
    size_t idx = (size_t)blockIdx.x * 256 + threadIdx.x;
    int d = idx & (Dx - 1);
    size_t t = idx >> 9;
    float v = ldsel(x, x, t * 2, f32)     * ldsel(We, We, d * 2, f32) +
              ldsel(x, x, t * 2 + 1, f32) * ldsel(We, We, d * 2 + 1, f32) +
              ldsel(be, be, d, f32);
    h[idx] = v;
}

// ---------------------------------------------------------------------------
// Split-bf16 MFMA GEMM, 128x64 tile, BK=32, LDS double-buffer + reg prefetch.
// BL: 0 W[n*K+k] (k-contig: W1, W2) ; 2 W[k*N+n] (n-contig: Wo flat)
// EPI: 1 +bias,relu ; 2 +bias(opt)+resid
// A16: A is bf16 row-major (no lo plane, 2 MFMAs/tile) ; else fp32 split (3)
// OBF: output bf16 ; else fp32
// ---------------------------------------------------------------------------
template <int BL, int EPI, int A16, int OBF>
__global__ __launch_bounds__(256) void gemm_mfma(
    const void* __restrict__ A,
    const void* __restrict__ W32, const void* __restrict__ W16,
    const void* __restrict__ bias32, const void* __restrict__ bias16,
    const float* __restrict__ resid,
    void* __restrict__ outp, int M, int N, int K, const int* __restrict__ dtp)
{
    const int f32 = *dtp;
    __shared__ __align__(16) __bf16 Ah[2][128][40];
    __shared__ __align__(16) __bf16 Al[A16 ? 1 : 2][A16 ? 1 : 128][A16 ? 8 : 40];
    __shared__ __align__(16) __bf16 Bh[2][64][40];
    __shared__ __align__(16) __bf16 Bl[2][64][40];

    const int tid = threadIdx.x;
    const int bm = blockIdx.y * 128;
    const int bn = blockIdx.x * 64;
    const int lane = tid & 63, wv = tid >> 6;
    const int quad = lane >> 4, lrow = lane & 15;
    const int wm = wv * 32;

    f32x4 acc[2][4] = {};

    const int ar = tid >> 1, akq = (tid & 1) * 16;
    const int br0 = tid >> 2, bkq0 = (tid & 3) * 8;   // BL0
    const int bgk = tid >> 3, bn8 = (tid & 7) * 8;    // BL2

    f32x4 pa[4];
    bfrag8 pa16[2];
    f32x4 pb[2];

    auto loadA = [&](int k0) {
        if constexpr (A16) {
            const __bf16* ap = (const __bf16*)A + (size_t)(bm + ar) * K + k0 + akq;
            pa16[0] = *(const bfrag8*)ap;
            pa16[1] = *(const bfrag8*)(ap + 8);
        } else {
            const float* ap = (const float*)A + (size_t)(bm + ar) * K + k0 + akq;
            pa[0] = *(const f32x4*)ap;
            pa[1] = *(const f32x4*)(ap + 4);
            pa[2] = *(const f32x4*)(ap + 8);
            pa[3] = *(const f32x4*)(ap + 12);
        }
    };
    auto loadB = [&](int k0) {
        if constexpr (BL == 0) {
            if (f32) {
                const float* wp = (const float*)W32 + (size_t)(bn + br0) * K + k0 + bkq0;
                pb[0] = *(const f32x4*)wp;
                pb[1] = *(const f32x4*)(wp + 4);
            } else {
                size_t base = (size_t)(bn + br0) * K + k0 + bkq0;
                #pragma unroll
                for (int j = 0; j < 4; ++j) {
                    pb[0][j] = ldsel(W32, W16, base + j, 0);
                    pb[1][j] = ldsel(W32, W16, base + 4 + j, 0);
                }
            }
        } else {
            if (f32) {
                const float* wp = (const float*)W32 + (size_t)(k0 + bgk) * N + bn + bn8;
                pb[0] = *(const f32x4*)wp;
                pb[1] = *(const f32x4*)(wp + 4);
            } else {
                size_t base = (size_t)(k0 + bgk) * N + bn + bn8;
                #pragma unroll
                for (int j = 0; j < 4; ++j) {
                    pb[0][j] = ldsel(W32, W16, base + j, 0);
                    pb[1][j] = ldsel(W32, W16, base + 4 + j, 0);
                }
            }
        }
    };
    auto storeAB = [&](int buf) {
        if constexpr (A16) {
            *(bfrag8*)&Ah[buf][ar][akq]     = pa16[0];
            *(bfrag8*)&Ah[buf][ar][akq + 8] = pa16[1];
        } else {
            #pragma unroll
            for (int half = 0; half < 2; ++half) {
                bfrag8 hi, lo;
                #pragma unroll
                for (int j = 0; j < 4; ++j) {
                    bf2 s0 = split2(pa[half * 2][j]);     hi[j] = s0.hi;     lo[j] = s0.lo;
                    bf2 s1 = split2(pa[half * 2 + 1][j]); hi[j + 4] = s1.hi; lo[j + 4] = s1.lo;
                }
                *(bfrag8*)&Ah[buf][ar][akq + half * 8] = hi;
                *(bfrag8*)&Al[buf][ar][akq + half * 8] = lo;
            }
        }
        if constexpr (BL == 0) {
            bfrag8 hi, lo;
            #pragma unroll
            for (int j = 0; j < 4; ++j) {
                bf2 s0 = split2(pb[0][j]); hi[j] = s0.hi;     lo[j] = s0.lo;
                bf2 s1 = split2(pb[1][j]); hi[j + 4] = s1.hi; lo[j + 4] = s1.lo;
            }
            *(bfrag8*)&Bh[buf][br0][bkq0] = hi;
            *(bfrag8*)&Bl[buf][br0][bkq0] = lo;
        } else {
            #pragma unroll
            for (int j = 0; j < 4; ++j) {
                bf2 s0 = split2(pb[0][j]); Bh[buf][bn8 + j][bgk] = s0.hi;     Bl[buf][bn8 + j][bgk] = s0.lo;
                bf2 s1 = split2(pb[1][j]); Bh[buf][bn8 + 4 + j][bgk] = s1.hi; Bl[buf][bn8 + 4 + j][bgk] = s1.lo;
            }
        }
    };

    loadA(0); loadB(0);
    storeAB(0);
    __syncthreads();

    int cur = 0;
    for (int k0 = 0; k0 < K; k0 += 32) {
        const bool more = (k0 + 32 < K);
        if (more) { loadA(k0 + 32); loadB(k0 + 32); }

        bfrag8 ah[2], alo[2], bh[4], blo[4];
        #pragma unroll
        for (int mt = 0; mt < 2; ++mt) {
            ah[mt] = *(const bfrag8*)&Ah[cur][wm + mt * 16 + lrow][quad * 8];
            if constexpr (!A16) alo[mt] = *(const bfrag8*)&Al[cur][wm + mt * 16 + lrow][quad * 8];
        }
        #pragma unroll
        for (int nt = 0; nt < 4; ++nt) {
            bh[nt]  = *(const bfrag8*)&Bh[cur][nt * 16 + lrow][quad * 8];
            blo[nt] = *(const bfrag8*)&Bl[cur][nt * 16 + lrow][quad * 8];
        }
        #pragma unroll
        for (int mt = 0; mt < 2; ++mt)
            #pragma unroll
            for (int nt = 0; nt < 4; ++nt) {
                acc[mt][nt] = __builtin_amdgcn_mfma_f32_16x16x32_bf16(ah[mt], bh[nt],  acc[mt][nt], 0, 0, 0);
                acc[mt][nt] = __builtin_amdgcn_mfma_f32_16x16x32_bf16(ah[mt], blo[nt], acc[mt][nt], 0, 0, 0);
                if constexpr (!A16)
                    acc[mt][nt] = __builtin_amdgcn_mfma_f32_16x16x32_bf16(alo[mt], bh[nt], acc[mt][nt], 0, 0, 0);
            }

        if (more) {
            storeAB(cur ^ 1);
            __syncthreads();
            cur ^= 1;
        }
    }

    #pragma unroll
    for (int mt = 0; mt < 2; ++mt)
        #pragma unroll
        for (int nt = 0; nt < 4; ++nt)
            #pragma unroll
            for (int reg = 0; reg < 4; ++reg) {
                int m = bm + wm + mt * 16 + quad * 4 + reg;
                int n = bn + nt * 16 + lrow;
                float v = acc[mt][nt][reg];
                if constexpr (EPI == 1) { v += ldsel(bias32, bias16, n, f32); v = fmaxf(v, 0.f); }
                if constexpr (EPI == 2) {
                    if (bias32) v += ldsel(bias32, bias16, n, f32);
                    v += resid[(size_t)m * N + n];
                }
                if constexpr (OBF) ((__bf16*)outp)[(size_t)m * N + n] = (__bf16)v;
                else               ((float*)outp)[(size_t)m * N + n] = v;
            }
}

// ---------------------------------------------------------------------------
// Fused QKV projection (full batch): N=1536.
// Q,K written as PRE-SPLIT bf16 hi/lo planes [H,B,N,DK] (same bytes as fp32).
// V written fp16, PRE-TRANSPOSED [H,B,DK,N] — attn stages it with vector copies.
// ---------------------------------------------------------------------------
__global__ __launch_bounds__(256) void qkv_mfma(
    const float* __restrict__ A,
    const void* __restrict__ Wq32, const void* __restrict__ Wq16,
    const void* __restrict__ Wk32, const void* __restrict__ Wk16,
    const void* __restrict__ Wv32, const void* __restrict__ Wv16,
    __bf16* __restrict__ Qhg, __bf16* __restrict__ Qlg,
    __bf16* __restrict__ Khg, __bf16* __restrict__ Klg,
    _Float16* __restrict__ Vo,
    int M, int K, const int* __restrict__ dtp)
{
    const int f32 = *dtp;
    __shared__ __align__(16) __bf16 Ah[2][128][40];
    __shared__ __align__(16) __bf16 Al[2][128][40];
    __shared__ __align__(16) __bf16 Bh[2][64][40];
    __shared__ __align__(16) __bf16 Bl[2][64][40];

    const int tid = threadIdx.x;
    const int bm = blockIdx.y * 128;
    const int bn = blockIdx.x * 64;            // 0..1536
    const int sel = bn >> 9;
    const int head = (bn & 511) >> 6;
    const void* W32 = (sel == 0) ? Wq32 : (sel == 1) ? Wk32 : Wv32;
    const void* W16 = (sel == 0) ? Wq16 : (sel == 1) ? Wk16 : Wv16;

    const int lane = tid & 63, wv = tid >> 6;
    const int quad = lane >> 4, lrow = lane & 15;
    const int wm = wv * 32;

    f32x4 acc[2][4] = {};
    const int ar = tid >> 1, akq = (tid & 1) * 16;
    const int bgk = tid >> 3, bn8 = (tid & 7) * 8;
    const size_t wbase = (size_t)head * K * 64;

    f32x4 pa[4];
    f32x4 pb[2];

    auto loadA = [&](int k0) {
        const float* ap = A + (size_t)(bm + ar) * K + k0 + akq;
        pa[0] = *(const f32x4*)ap;
        pa[1] = *(const f32x4*)(ap + 4);
        pa[2] = *(const f32x4*)(ap + 8);
        pa[3] = *(const f32x4*)(ap + 12);
    };
    auto loadB = [&](int k0) {
        if (f32) {
            const float* wp = (const float*)W32 + wbase + (size_t)(k0 + bgk) * 64 + bn8;
            pb[0] = *(const f32x4*)wp;
            pb[1] = *(const f32x4*)(wp + 4);
        } else {
            size_t base = wbase + (size_t)(k0 + bgk) * 64 + bn8;
            #pragma unroll
            for (int j = 0; j < 4; ++j) {
                pb[0][j] = ldsel(W32, W16, base + j, 0);
                pb[1][j] = ldsel(W32, W16, base + 4 + j, 0);
            }
        }
    };
    auto storeAB = [&](int buf) {
        #pragma unroll
        for (int half = 0; half < 2; ++half) {
            bfrag8 hi, lo;
            #pragma unroll
            for (int j = 0; j < 4; ++j) {
                bf2 s0 = split2(pa[half * 2][j]);     hi[j] = s0.hi;     lo[j] = s0.lo;
                bf2 s1 = split2(pa[half * 2 + 1][j]); hi[j + 4] = s1.hi; lo[j + 4] = s1.lo;
            }
            *(bfrag8*)&Ah[buf][ar][akq + half * 8] = hi;
            *(bfrag8*)&Al[buf][ar][akq + half * 8] = lo;
        }
        #pragma unroll
        for (int j = 0; j < 4; ++j) {
            bf2 s0 = split2(pb[0][j]); Bh[buf][bn8 + j][bgk] = s0.hi;     Bl[buf][bn8 + j][bgk] = s0.lo;
            bf2 s1 = split2(pb[1][j]); Bh[buf][bn8 + 4 + j][bgk] = s1.hi; Bl[buf][bn8 + 4 + j][bgk] = s1.lo;
        }
    };

    loadA(0); loadB(0);
    storeAB(0);
    __syncthreads();

    int cur = 0;
    for (int k0 = 0; k0 < K; k0 += 32) {
        const bool more = (k0 + 32 < K);
        if (more) { loadA(k0 + 32); loadB(k0 + 32); }

        bfrag8 ah[2], alo[2], bh[4], blo[4];
        #pragma unroll
        for (int mt = 0; mt < 2; ++mt) {
            ah[mt]  = *(const bfrag8*)&Ah[cur][wm + mt * 16 + lrow][quad * 8];
            alo[mt] = *(const bfrag8*)&Al[cur][wm + mt * 16 + lrow][quad * 8];
        }
        #pragma unroll
        for (int nt = 0; nt < 4; ++nt) {
            bh[nt]  = *(const bfrag8*)&Bh[cur][nt * 16 + lrow][quad * 8];
            blo[nt] = *(const bfrag8*)&Bl[cur][nt * 16 + lrow][quad * 8];
        }
        #pragma unroll
        for (int mt = 0; mt < 2; ++mt)
            #pragma unroll
            for (int nt = 0; nt < 4; ++nt) {
                acc[mt][nt] = __builtin_amdgcn_mfma_f32_16x16x32_bf16(ah[mt],  bh[nt],  acc[mt][nt], 0, 0, 0);
                acc[mt][nt] = __builtin_amdgcn_mfma_f32_16x16x32_bf16(ah[mt],  blo[nt], acc[mt][nt], 0, 0, 0);
                acc[mt][nt] = __builtin_amdgcn_mfma_f32_16x16x32_bf16(alo[mt], bh[nt],  acc[mt][nt], 0, 0, 0);
            }

        if (more) {
            storeAB(cur ^ 1);
            __syncthreads();
            cur ^= 1;
        }
    }

    const int nb = M >> 9;   // batches (32)
    #pragma unroll
    for (int mt = 0; mt < 2; ++mt)
        #pragma unroll
        for (int nt = 0; nt < 4; ++nt) {
            const int dk = nt * 16 + lrow;
            const int m0 = bm + wm + mt * 16 + quad * 4;
            const int b_ = m0 >> 9, q = m0 & 511;
            if (sel == 2) {
                // transposed fp16 V: [H, B, DK, N]; q is 4-aligned -> 8B store
                h4 v;
                #pragma unroll
                for (int reg = 0; reg < 4; ++reg) v[reg] = (_Float16)acc[mt][nt][reg];
                *(h4*)&Vo[(((size_t)head * nb + b_) * DKx + dk) * Nx + q] = v;
            } else {
                __bf16* hp = (sel == 1) ? Khg : Qhg;
                __bf16* lp = (sel == 1) ? Klg : Qlg;
                #pragma unroll
                for (int reg = 0; reg < 4; ++reg) {
                    float v = acc[mt][nt][reg];
                    __bf16 hi = (__bf16)v;
                    size_t oidx = (((size_t)head * nb + b_) * Nx + (q + reg)) * DKx + dk;
                    hp[oidx] = hi;
                    lp[oidx] = (__bf16)(v - (float)hi);
                }
            }
        }
}

// ---------------------------------------------------------------------------
// MFMA flash attention: Q,K bf16 hi/lo planes [H,B,N,DK]; V fp16 [H,B,DK,N].
// Q frags in registers; single K/V LDS buffer + register prefetch;
// wave-parallel softmax (4 lanes/row, shfl reduce); S/P share one fp16 buffer.
// LDS 37.6 KB -> 4 blocks/CU.
// ---------------------------------------------------------------------------
__global__ __launch_bounds__(256, 4) void attn_kernel(
    const __bf16* __restrict__ Qhg, const __bf16* __restrict__ Qlg,
    const __bf16* __restrict__ Khg, const __bf16* __restrict__ Klg,
    const _Float16* __restrict__ Vtg, float* __restrict__ heads)
{
    __shared__ __align__(16) __bf16    Kh[64][72], Kl[64][72];
    __shared__ __align__(16) _Float16  Vt[64][72];
    __shared__ __align__(16) _Float16  Sp[64][72];
    __shared__ float ml[64], ll[64], al[64];

    const int tid = threadIdx.x;
    const int q0 = blockIdx.x * 64;
    const int hb = blockIdx.y;                 // h*Bx + b
    const size_t base = (size_t)hb * (Nx * DKx);
    const int lane = tid & 63, wv = tid >> 6;
    const int quad = lane >> 4, lrow = lane & 15;
    const int wm = (wv & 1) * 32, wn = (wv >> 1) * 32;
    const int sr = tid >> 2, sc = (tid & 3) * 16;   // staging row / col

    // ---- stage Q through Kh/Kl once, pull fragments to registers ----
    {
        size_t off = base + (size_t)(q0 + sr) * DKx + sc;
        *(bfrag8*)&Kh[sr][sc]     = *(const bfrag8*)(Qhg + off);
        *(bfrag8*)&Kh[sr][sc + 8] = *(const bfrag8*)(Qhg + off + 8);
        *(bfrag8*)&Kl[sr][sc]     = *(const bfrag8*)(Qlg + off);
        *(bfrag8*)&Kl[sr][sc + 8] = *(const bfrag8*)(Qlg + off + 8);
    }
    if (tid < 64) { ml[tid] = -INFINITY; ll[tid] = 0.f; }
    __syncthreads();

    bfrag8 qh[2][2], qlo[2][2];
    #pragma unroll
    for (int mt = 0; mt < 2; ++mt)
        #pragma unroll
        for (int ks = 0; ks < 2; ++ks) {
            qh[mt][ks]  = *(const bfrag8*)&Kh[wm + mt * 16 + lrow][ks * 32 + quad * 8];
            qlo[mt][ks] = *(const bfrag8*)&Kl[wm + mt * 16 + lrow][ks * 32 + quad * 8];
        }
    __syncthreads();   // Q frags pulled; Kh/Kl now free for K staging

    bfrag8 pkh[2], pkl[2];
    hfrag8 pv[2];
    auto loadKV = [&](int n0) {
        size_t off = base + (size_t)(n0 + sr) * DKx + sc;
        pkh[0] = *(const bfrag8*)(Khg + off);
        pkh[1] = *(const bfrag8*)(Khg + off + 8);
        pkl[0] = *(const bfrag8*)(Klg + off);
        pkl[1] = *(const bfrag8*)(Klg + off + 8);
        const _Float16* vp = Vtg + base + (size_t)sr * Nx + n0 + sc;
        pv[0] = *(const hfrag8*)vp;
        pv[1] = *(const hfrag8*)(vp + 8);
    };
    auto storeKV = [&]() {
        *(bfrag8*)&Kh[sr][sc]     = pkh[0];
        *(bfrag8*)&Kh[sr][sc + 8] = pkh[1];
        *(bfrag8*)&Kl[sr][sc]     = pkl[0];
        *(bfrag8*)&Kl[sr][sc + 8] = pkl[1];
        *(hfrag8*)&Vt[sr][sc]     = pv[0];
        *(hfrag8*)&Vt[sr][sc + 8] = pv[1];
    };

    f32x4 accO[2][2] = {};

    loadKV(0); storeKV();
    __syncthreads();

    for (int n0 = 0; n0 < Nx; n0 += 64) {
        const bool more = (n0 + 64 < Nx);
        if (more) loadKV(n0 + 64);     // prefetch next tile; latency hidden below

        // ---- QK^T (split-bf16, 3 MFMAs) ----
        f32x4 accS[2][2] = {};
        #pragma unroll
        for (int ks = 0; ks < 2; ++ks) {
            bfrag8 bh[2], blo[2];
            #pragma unroll
            for (int nt = 0; nt < 2; ++nt) {
                bh[nt]  = *(const bfrag8*)&Kh[wn + nt * 16 + lrow][ks * 32 + quad * 8];
                blo[nt] = *(const bfrag8*)&Kl[wn + nt * 16 + lrow][ks * 32 + quad * 8];
            }
            #pragma unroll
            for (int mt = 0; mt < 2; ++mt)
                #pragma unroll
                for (int nt = 0; nt < 2; ++nt) {
                    accS[mt][nt] = __builtin_amdgcn_mfma_f32_16x16x32_bf16(qh[mt][ks],  bh[nt],  accS[mt][nt], 0, 0, 0);
                    accS[mt][nt] = __builtin_amdgcn_mfma_f32_16x16x32_bf16(qh[mt][ks],  blo[nt], accS[mt][nt], 0, 0, 0);
                    accS[mt][nt] = __builtin_amdgcn_mfma_f32_16x16x32_bf16(qlo[mt][ks], bh[nt],  accS[mt][nt], 0, 0, 0);
                }
        }
        // scores -> Sp (fp16, scaled)
        #pragma unroll
        for (int mt = 0; mt < 2; ++mt)
            #pragma unroll
            for (int nt = 0; nt < 2; ++nt)
                #pragma unroll
                for (int reg = 0; reg < 4; ++reg)
                    Sp[wm + mt * 16 + quad * 4 + reg][wn + nt * 16 + lrow] =
                        (_Float16)(accS[mt][nt][reg] * 0.125f);
        __syncthreads();

        // ---- wave-parallel online softmax: 4 lanes per row, 16 cols each ----
        {
            hfrag8 s0 = *(const hfrag8*)&Sp[sr][sc];
            hfrag8 s1 = *(const hfrag8*)&Sp[sr][sc + 8];
            float rmax = -INFINITY;
            #pragma unroll
            for (int j = 0; j < 8; ++j) {
                rmax = fmaxf(rmax, (float)s0[j]);
                rmax = fmaxf(rmax, (float)s1[j]);
            }
            rmax = fmaxf(rmax, __shfl_xor(rmax, 1));
            rmax = fmaxf(rmax, __shfl_xor(rmax, 2));
            float mold = ml[sr];
            float mnew = fmaxf(mold, rmax);
            float sum = 0.f;
            hfrag8 p0, p1;
            #pragma unroll
            for (int j = 0; j < 8; ++j) {
                float pa = __expf((float)s0[j] - mnew);
                float pb = __expf((float)s1[j] - mnew);
                sum += pa + pb;
                p0[j] = (_Float16)pa;
                p1[j] = (_Float16)pb;
            }
            sum += __shfl_xor(sum, 1);
            sum += __shfl_xor(sum, 2);
            // in-place P write: same 16 slots this thread just read (no WAR)
            *(hfrag8*)&Sp[sr][sc]     = p0;
            *(hfrag8*)&Sp[sr][sc + 8] = p1;
            if ((tid & 3) == 0) {
                float alpha = __expf(mold - mnew);
                ml[sr] = mnew;
                ll[sr] = ll[sr] * alpha + sum;
                al[sr] = alpha;
            }
        }
        __syncthreads();

        // ---- rescale O, then P*V (fp16 MFMA) ----
        #pragma unroll
        for (int mt = 0; mt < 2; ++mt) {
            float a0 = al[wm + mt * 16 + quad * 4 + 0];
            float a1 = al[wm + mt * 16 + quad * 4 + 1];
            float a2 = al[wm + mt * 16 + quad * 4 + 2];
            float a3 = al[wm + mt * 16 + quad * 4 + 3];
            #pragma unroll
            for (int nt = 0; nt < 2; ++nt) {
                accO[mt][nt][0] *= a0; accO[mt][nt][1] *= a1;
                accO[mt][nt][2] *= a2; accO[mt][nt][3] *= a3;
            }
        }
        #pragma unroll
        for (int ks = 0; ks < 2; ++ks) {
            hfrag8 ap[2], bv[2];
            #pragma unroll
            for (int mt = 0; mt < 2; ++mt)
                ap[mt] = *(const hfrag8*)&Sp[wm + mt * 16 + lrow][ks * 32 + quad * 8];
            #pragma unroll
            for (int nt = 0; nt < 2; ++nt)
                bv[nt] = *(const hfrag8*)&Vt[wn + nt * 16 + lrow][ks * 32 + quad * 8];
            #pragma unroll
            for (int mt = 0; mt < 2; ++mt)
                #pragma unroll
                for (int nt = 0; nt < 2; ++nt)
                    accO[mt][nt] = __builtin_amdgcn_mfma_f32_16x16x32_f16(ap[mt], bv[nt], accO[mt][nt], 0, 0, 0);
        }

        if (more) {
            __syncthreads();   // all waves done reading Vt/Sp/Kh/Kl
            storeKV();
            __syncthreads();   // next tile visible
        }
    }

    const int h_ = hb >> 5, b_ = hb & 31;
    #pragma unroll
    for (int mt = 0; mt < 2; ++mt)
        #pragma unroll
        for (int reg = 0; reg < 4; ++reg) {
            int qrow = wm + mt * 16 + quad * 4 + reg;
            float invl = 1.f / ll[qrow];
            size_t tok = (size_t)b_ * Nx + (q0 + qrow);
            #pragma unroll
            for (int nt = 0; nt < 2; ++nt) {
                int dk = wn + nt * 16 + lrow;
                heads[tok * Dx + h_ * DKx + dk] = accO[mt][nt][reg] * invl;
            }
        }
}

// ---------------------------------------------------------------------------
__global__ __launch_bounds__(256) void bn_stats(const float* __restrict__ t, float* __restrict__ stats)
{
    int r0 = blockIdx.x * 16;
    int c = threadIdx.x;
    float s0 = 0, q0 = 0, s1 = 0, q1 = 0;
    for (int r = 0; r < 16; ++r) {
        const float* row = t + (size_t)(r0 + r) * Dx;
        float v0 = row[c], v1 = row[c + 256];
        s0 += v0; q0 += v0 * v0; s1 += v1; q1 += v1 * v1;
    }
    atomicAdd(&stats[c], s0);
    atomicAdd(&stats[c + 256], s1);
    atomicAdd(&stats[Dx + c], q0);
    atomicAdd(&stats[Dx + c + 256], q1);
}

__global__ __launch_bounds__(256) void bn_norm(
    const float* __restrict__ t, const float* __restrict__ stats,
    const void* __restrict__ g32, const void* __restrict__ g16,
    const void* __restrict__ b32, const void* __restrict__ b16,
    float* __restrict__ h, const int* __restrict__ dtp)
{
    const int f32 = *dtp;
    size_t idx = (size_t)blockIdx.x * 256 + threadIdx.x;
    int c = idx & (Dx - 1);
    const float invM = 1.f / (float)TOK;
    float mu = stats[c] * invM;
    float var = stats[Dx + c] * invM - mu * mu;
    float v = (t[idx] - mu) * rsqrtf(var + EPSx) * ldsel(g32, g16, c, f32) + ldsel(b32, b16, c, f32);
    h[idx] = v;
}

// ---------------------------------------------------------------------------
__global__ __launch_bounds__(256) void out_h_kernel(const float* __restrict__ h, float* __restrict__ out)
{
    size_t idx = (size_t)blockIdx.x * 256 + threadIdx.x;
    out[idx] = h[idx];
}

__global__ __launch_bounds__(512) void out_mean_kernel(const float* __restrict__ h, float* __restrict__ out2)
{
    int b = blockIdx.x;
    int d = threadIdx.x;
    float s = 0.f;
    for (int n = 0; n < Nx; ++n) s += h[((size_t)b * Nx + n) * Dx + d];
    out2[b * Dx + d] = s * (1.f / (float)Nx);
}

// ---------------------------------------------------------------------------
extern "C" void kernel_launch(void* const* d_in, const int* in_sizes, int n_in,
                              void* d_out, int out_size, void* d_ws, size_t ws_size,
                              hipStream_t stream)
{
    const void* x   = d_in[0];
    const void* We  = d_in[1];
    const void* be  = d_in[2];
    const void* Wq  = d_in[3];
    const void* Wk  = d_in[4];
    const void* Wv  = d_in[5];
    const void* Wo  = d_in[6];
    const void* g1  = d_in[7];
    const void* b1  = d_in[8];
    const void* W1  = d_in[9];
    const void* bb1 = d_in[10];
    const void* W2  = d_in[11];
    const void* bb2 = d_in[12];
    const void* g2  = d_in[13];
    const void* b2  = d_in[14];

    const size_t szWqkv = (size_t)Hx * Dx * DKx;
    const size_t szWo   = (size_t)Hx * DKx * Dx;
    const size_t szW1   = (size_t)FFx * Dx;
    const size_t szW2   = (size_t)Dx * FFx;

    // workspace: h(32MB) | t(32MB) | stats/dtp | region(~117MB)
    float* h     = (float*)d_ws;
    float* t     = h + (size_t)TOK * Dx;
    float* stats = t + (size_t)TOK * Dx;
    int*   dtp   = (int*)(stats + 2 * Dx);
    float* region = stats + 2 * Dx + 64;
    // attention-phase views (same total bytes as before):
    //   heads fp32 32MB | Qh/Ql/Kh/Kl bf16 planes 4x16.8MB | V^T fp16 16.8MB
    const size_t QKN = (size_t)Hx * Bx * Nx * DKx;   // 8.4M elems
    float*    heads = region;
    __bf16*   Qhg   = (__bf16*)(heads + (size_t)TOK * Dx);
    __bf16*   Qlg   = Qhg + QKN;
    __bf16*   Khg   = Qlg + QKN;
    __bf16*   Klg   = Khg + QKN;
    _Float16* Vtg   = (_Float16*)(Klg + QKN);
    // FF-phase view: ffbuf bf16 [TOK, FFx] = 64 MB (overlaps heads/Q)
    __bf16* ffbuf = (__bf16*)region;

    auto p32 = [](const void* p, size_t e) { return (const void*)((const float*)p + e); };
    auto p16 = [](const void* p, size_t e) { return (const void*)((const __hip_bfloat16*)p + e); };

    detect_kernel<<<1, 64, 0, stream>>>(x, dtp);
    embed_kernel<<<TOK * Dx / 256, 256, 0, stream>>>(x, We, be, h, dtp);

    const dim3 gQKV(24, TOK / 128);                   // (24, 128)
    const dim3 gWo(Dx / 64, TOK / 128);               // (8, 128)
    const dim3 gAttn(Nx / 64, Hx * Bx);               // (8, 256)
    const dim3 gFF1(FFx / 64, TOK / 128);             // (32, 128)
    const dim3 gFF2(Dx / 64, TOK / 128);              // (8, 128)
    for (int l = 0; l < 3; ++l) {
        const size_t eW = (size_t)l * szWqkv, eO = (size_t)l * szWo;
        const size_t e1 = (size_t)l * szW1,  e2 = (size_t)l * szW2;
        const size_t eD = (size_t)l * Dx,    eF = (size_t)l * FFx;

        qkv_mfma<<<gQKV, 256, 0, stream>>>(
            h, p32(Wq, eW), p16(Wq, eW), p32(Wk, eW), p16(Wk, eW),
            p32(Wv, eW), p16(Wv, eW), Qhg, Qlg, Khg, Klg, Vtg, TOK, Dx, dtp);
        attn_kernel<<<gAttn, 256, 0, stream>>>(Qhg, Qlg, Khg, Klg, Vtg, heads);

        // output projection + residual: t = h + heads @ Wo_flat
        gemm_mfma<2, 2, 0, 0><<<gWo, 256, 0, stream>>>(
            heads, p32(Wo, eO), p16(Wo, eO), nullptr, nullptr, h, t, TOK, Dx, Dx, dtp);

        hipMemsetAsync(stats, 0, 2 * Dx * sizeof(float), stream);
        bn_stats<<<1024, 256, 0, stream>>>(t, stats);
        bn_norm<<<TOK * Dx / 256, 256, 0, stream>>>(
            t, stats, p32(g1, eD), p16(g1, eD), p32(b1, eD), p16(b1, eD), h, dtp);

        // FF: ffbuf bf16 [TOK, FFx]
        gemm_mfma<0, 1, 0, 1><<<gFF1, 256, 0, stream>>>(
            h, p32(W1, e1), p16(W1, e1), p32(bb1, eF), p16(bb1, eF), nullptr, ffbuf, TOK, FFx, Dx, dtp);
        gemm_mfma<0, 2, 1, 0><<<gFF2, 256, 0, stream>>>(
            ffbuf, p32(W2, e2), p16(W2, e2), p32(bb2, eD), p16(bb2, eD), h, t, TOK, Dx, FFx, dtp);

        hipMemsetAsync(stats, 0, 2 * Dx * sizeof(float), stream);
        bn_stats<<<1024, 256, 0, stream>>>(t, stats);
        bn_norm<<<TOK * Dx / 256, 256, 0, stream>>>(
            t, stats, p32(g2, eD), p16(g2, eD), p32(b2, eD), p16(b2, eD), h, dtp);
    }

    out_h_kernel<<<TOK * Dx / 256, 256, 0, stream>>>(h, (float*)d_out);
    out_mean_kernel<<<Bx, Dx, 0, stream>>>(h, (float*)d_out + (size_t)TOK * Dx);
}

// Round 2
// 1951.285 us; speedup vs baseline: 1.3275x; 1.1817x over previous
//
#include <hip/hip_runtime.h>
#include <hip/hip_bf16.h>

// Problem constants
#define Bx 32
#define Nx 512
#define Dx 512
#define Hx 8
#define DKx 64
#define FFx 2048
#define TOK (Bx * Nx)          // 16384 tokens
#define EPSx 1e-5f

typedef __bf16 bfrag8 __attribute__((ext_vector_type(8)));
typedef float  f32x4  __attribute__((ext_vector_type(4)));
typedef _Float16 hfrag8 __attribute__((ext_vector_type(8)));
typedef _Float16 h4     __attribute__((ext_vector_type(4)));

struct bf2 { __bf16 hi, lo; };
__device__ __forceinline__ bf2 split2(float v) {
    __bf16 h = (__bf16)v;
    bf2 r; r.hi = h; r.lo = (__bf16)(v - (float)h);
    return r;
}

// ---------------------------------------------------------------------------
__device__ __forceinline__ float ldsel(const void* p32, const void* p16, size_t i, int f32) {
    return f32 ? ((const float*)p32)[i]
               : __bfloat162float(((const __hip_bfloat16*)p16)[i]);
}

__global__ void detect_kernel(const void* __restrict__ x, int* __restrict__ flag)
{
    if (threadIdx.x == 0 && blockIdx.x == 0) {
        const unsigned short* u = (const unsigned short*)x;
        int hits = 0;
        for (int i = 0; i < 256; ++i) {
            int e = (u[i] >> 7) & 0xFF;
            if (e >= 0x86) ++hits;
        }
        *flag = (hits > 8) ? 1 : 0;
    }
}

// ---------------------------------------------------------------------------
// Weight conversion: elementwise split to bf16 hi/lo planes.
__global__ __launch_bounds__(256) void split_kernel(
    const void* __restrict__ W, __bf16* __restrict__ oh, __bf16* __restrict__ ol,
    const int* __restrict__ dtp)
{
    const int f32 = *dtp;
    size_t idx = (size_t)blockIdx.x * 256 + threadIdx.x;
    bf2 s = split2(ldsel(W, W, idx, f32));
    oh[idx] = s.hi; ol[idx] = s.lo;
}

// Weight conversion: transpose [R][C] -> [C][R] per matrix (blockIdx.z), split.
__global__ __launch_bounds__(256) void transpose_split_kernel(
    const void* __restrict__ W, __bf16* __restrict__ oh, __bf16* __restrict__ ol,
    int R, int C, const int* __restrict__ dtp)
{
    const int f32 = *dtp;
    __shared__ float tile[64][65];
    const size_t mbase = (size_t)blockIdx.z * R * C;
    const int c0 = blockIdx.x * 64, r0 = blockIdx.y * 64;
    const int tc = threadIdx.x & 63, tg = threadIdx.x >> 6;
    #pragma unroll
    for (int i = 0; i < 16; ++i) {
        int r = tg * 16 + i;
        tile[r][tc] = ldsel(W, W, mbase + (size_t)(r0 + r) * C + c0 + tc, f32);
    }
    __syncthreads();
    #pragma unroll
    for (int i = 0; i < 16; ++i) {
        int cc = tg * 16 + i;
        bf2 s = split2(tile[tc][cc]);
        size_t o = mbase + (size_t)(c0 + cc) * R + r0 + tc;
        oh[o] = s.hi; ol[o] = s.lo;
    }
}

// ---------------------------------------------------------------------------
__global__ __launch_bounds__(256) void embed_kernel(
    const void* __restrict__ x, const void* __restrict__ We,
    const void* __restrict__ be, __bf16* __restrict__ hh, __bf16* __restrict__ hl,
    const int* __restrict__ dtp)
{
    const int f32 = *dtp;
    size_t idx = (size_t)blockIdx.x * 256 + threadIdx.x;
    int d = idx & (Dx - 1);
    size_t t = idx >> 9;
    float v = ldsel(x, x, t * 2, f32)     * ldsel(We, We, d * 2, f32) +
              ldsel(x, x, t * 2 + 1, f32) * ldsel(We, We, d * 2 + 1, f32) +
              ldsel(be, be, d, f32);
    bf2 s = split2(v);
    hh[idx] = s.hi; hl[idx] = s.lo;
}

// ---------------------------------------------------------------------------
// MFMA GEMM on pre-split bf16 planes. 128x64 tile, BK=32.
// Single LDS buffer + register prefetch (2 barriers/iter), 4 blocks/CU.
// A: row-major [M][K] planes (ASPLIT=1: hi only, 2 MFMA; ASPLIT=2: hi+lo, 3 MFMA)
// B: k-contiguous [N][K] hi/lo planes.
// EPI: 1 +bias,relu ; 2 +bias(opt)+resid(planes)
// OBF: output bf16 ; else fp32
// ---------------------------------------------------------------------------
template <int ASPLIT, int EPI, int OBF>
__global__ __launch_bounds__(256, 4) void gemm2(
    const __bf16* __restrict__ Ahg, const __bf16* __restrict__ Alg,
    const __bf16* __restrict__ Bhg, const __bf16* __restrict__ Blg,
    const void* __restrict__ bias32, const void* __restrict__ bias16,
    const __bf16* __restrict__ residH, const __bf16* __restrict__ residL,
    void* __restrict__ outp, int M, int N, int K, const int* __restrict__ dtp)
{
    const int f32 = *dtp;
    __shared__ __align__(16) __bf16 Ah[128][40];
    __shared__ __align__(16) __bf16 Al[ASPLIT == 2 ? 128 : 1][ASPLIT == 2 ? 40 : 8];
    __shared__ __align__(16) __bf16 Bh[64][40];
    __shared__ __align__(16) __bf16 Bl[64][40];

    const int tid = threadIdx.x;
    const int bm = blockIdx.y * 128;
    const int bn = blockIdx.x * 64;
    const int lane = tid & 63, wv = tid >> 6;
    const int quad = lane >> 4, lrow = lane & 15;
    const int wm = wv * 32;

    f32x4 acc[2][4] = {};
    const int ar = tid >> 1, akq = (tid & 1) * 16;
    const int br = tid >> 2, bkq = (tid & 3) * 8;

    bfrag8 pah[2], pal[2], pbh, pbl;
    auto loadAB = [&](int k0) {
        const __bf16* ap = Ahg + (size_t)(bm + ar) * K + k0 + akq;
        pah[0] = *(const bfrag8*)ap;
        pah[1] = *(const bfrag8*)(ap + 8);
        if constexpr (ASPLIT == 2) {
            const __bf16* alp = Alg + (size_t)(bm + ar) * K + k0 + akq;
            pal[0] = *(const bfrag8*)alp;
            pal[1] = *(const bfrag8*)(alp + 8);
        }
        pbh = *(const bfrag8*)(Bhg + (size_t)(bn + br) * K + k0 + bkq);
        pbl = *(const bfrag8*)(Blg + (size_t)(bn + br) * K + k0 + bkq);
    };
    auto storeAB = [&]() {
        *(bfrag8*)&Ah[ar][akq]     = pah[0];
        *(bfrag8*)&Ah[ar][akq + 8] = pah[1];
        if constexpr (ASPLIT == 2) {
            *(bfrag8*)&Al[ar][akq]     = pal[0];
            *(bfrag8*)&Al[ar][akq + 8] = pal[1];
        }
        *(bfrag8*)&Bh[br][bkq] = pbh;
        *(bfrag8*)&Bl[br][bkq] = pbl;
    };

    loadAB(0); storeAB();
    __syncthreads();

    for (int k0 = 0; k0 < K; k0 += 32) {
        const bool more = (k0 + 32 < K);
        if (more) loadAB(k0 + 32);

        bfrag8 ah[2], alo[2];
        #pragma unroll
        for (int mt = 0; mt < 2; ++mt) {
            ah[mt] = *(const bfrag8*)&Ah[wm + mt * 16 + lrow][quad * 8];
            if constexpr (ASPLIT == 2) alo[mt] = *(const bfrag8*)&Al[wm + mt * 16 + lrow][quad * 8];
        }
        #pragma unroll
        for (int nt = 0; nt < 4; ++nt) {
            bfrag8 bh = *(const bfrag8*)&Bh[nt * 16 + lrow][quad * 8];
            bfrag8 bl = *(const bfrag8*)&Bl[nt * 16 + lrow][quad * 8];
            #pragma unroll
            for (int mt = 0; mt < 2; ++mt) {
                acc[mt][nt] = __builtin_amdgcn_mfma_f32_16x16x32_bf16(ah[mt], bh, acc[mt][nt], 0, 0, 0);
                acc[mt][nt] = __builtin_amdgcn_mfma_f32_16x16x32_bf16(ah[mt], bl, acc[mt][nt], 0, 0, 0);
                if constexpr (ASPLIT == 2)
                    acc[mt][nt] = __builtin_amdgcn_mfma_f32_16x16x32_bf16(alo[mt], bh, acc[mt][nt], 0, 0, 0);
            }
        }

        if (more) {
            __syncthreads();
            storeAB();
            __syncthreads();
        }
    }

    #pragma unroll
    for (int mt = 0; mt < 2; ++mt)
        #pragma unroll
        for (int nt = 0; nt < 4; ++nt)
            #pragma unroll
            for (int reg = 0; reg < 4; ++reg) {
                int m = bm + wm + mt * 16 + quad * 4 + reg;
                int n = bn + nt * 16 + lrow;
                float v = acc[mt][nt][reg];
                if constexpr (EPI == 1) { v += ldsel(bias32, bias16, n, f32); v = fmaxf(v, 0.f); }
                if constexpr (EPI == 2) {
                    if (bias32) v += ldsel(bias32, bias16, n, f32);
                    size_t ridx = (size_t)m * N + n;
                    v += (float)residH[ridx] + (float)residL[ridx];
                }
                if constexpr (OBF) ((__bf16*)outp)[(size_t)m * N + n] = (__bf16)v;
                else               ((float*)outp)[(size_t)m * N + n] = v;
            }
}

// ---------------------------------------------------------------------------
// Fused QKV projection: A = h planes; B = pre-transposed/split Wq/Wk/Wv planes
// ([H][DK][D] k-contig). Q,K out as bf16 hi/lo planes [H,B,N,DK];
// V out fp16 pre-transposed [H,B,DK,N].
// ---------------------------------------------------------------------------
__global__ __launch_bounds__(256, 4) void qkv_mfma(
    const __bf16* __restrict__ Ahg, const __bf16* __restrict__ Alg,
    const __bf16* __restrict__ QTh, const __bf16* __restrict__ QTl,
    const __bf16* __restrict__ KTh, const __bf16* __restrict__ KTl,
    const __bf16* __restrict__ VTh, const __bf16* __restrict__ VTl,
    __bf16* __restrict__ Qhg, __bf16* __restrict__ Qlg,
    __bf16* __restrict__ Khg, __bf16* __restrict__ Klg,
    _Float16* __restrict__ Vo, int M, int K)
{
    __shared__ __align__(16) __bf16 Ah[128][40];
    __shared__ __align__(16) __bf16 Al[128][40];
    __shared__ __align__(16) __bf16 Bh[64][40];
    __shared__ __align__(16) __bf16 Bl[64][40];

    const int tid = threadIdx.x;
    const int bm = blockIdx.y * 128;
    const int bn = blockIdx.x * 64;            // 0..1536
    const int sel = bn >> 9;
    const int head = (bn & 511) >> 6;
    const __bf16* Bhg = ((sel == 0) ? QTh : (sel == 1) ? KTh : VTh) + (size_t)head * DKx * Dx;
    const __bf16* Blg = ((sel == 0) ? QTl : (sel == 1) ? KTl : VTl) + (size_t)head * DKx * Dx;

    const int lane = tid & 63, wv = tid >> 6;
    const int quad = lane >> 4, lrow = lane & 15;
    const int wm = wv * 32;

    f32x4 acc[2][4] = {};
    const int ar = tid >> 1, akq = (tid & 1) * 16;
    const int br = tid >> 2, bkq = (tid & 3) * 8;

    bfrag8 pah[2], pal[2], pbh, pbl;
    auto loadAB = [&](int k0) {
        const __bf16* ap = Ahg + (size_t)(bm + ar) * K + k0 + akq;
        pah[0] = *(const bfrag8*)ap;
        pah[1] = *(const bfrag8*)(ap + 8);
        const __bf16* alp = Alg + (size_t)(bm + ar) * K + k0 + akq;
        pal[0] = *(const bfrag8*)alp;
        pal[1] = *(const bfrag8*)(alp + 8);
        pbh = *(const bfrag8*)(Bhg + (size_t)br * K + k0 + bkq);
        pbl = *(const bfrag8*)(Blg + (size_t)br * K + k0 + bkq);
    };
    auto storeAB = [&]() {
        *(bfrag8*)&Ah[ar][akq]     = pah[0];
        *(bfrag8*)&Ah[ar][akq + 8] = pah[1];
        *(bfrag8*)&Al[ar][akq]     = pal[0];
        *(bfrag8*)&Al[ar][akq + 8] = pal[1];
        *(bfrag8*)&Bh[br][bkq] = pbh;
        *(bfrag8*)&Bl[br][bkq] = pbl;
    };

    loadAB(0); storeAB();
    __syncthreads();

    for (int k0 = 0; k0 < K; k0 += 32) {
        const bool more = (k0 + 32 < K);
        if (more) loadAB(k0 + 32);

        bfrag8 ah[2], alo[2];
        #pragma unroll
        for (int mt = 0; mt < 2; ++mt) {
            ah[mt]  = *(const bfrag8*)&Ah[wm + mt * 16 + lrow][quad * 8];
            alo[mt] = *(const bfrag8*)&Al[wm + mt * 16 + lrow][quad * 8];
        }
        #pragma unroll
        for (int nt = 0; nt < 4; ++nt) {
            bfrag8 bh = *(const bfrag8*)&Bh[nt * 16 + lrow][quad * 8];
            bfrag8 bl = *(const bfrag8*)&Bl[nt * 16 + lrow][quad * 8];
            #pragma unroll
            for (int mt = 0; mt < 2; ++mt) {
                acc[mt][nt] = __builtin_amdgcn_mfma_f32_16x16x32_bf16(ah[mt],  bh, acc[mt][nt], 0, 0, 0);
                acc[mt][nt] = __builtin_amdgcn_mfma_f32_16x16x32_bf16(ah[mt],  bl, acc[mt][nt], 0, 0, 0);
                acc[mt][nt] = __builtin_amdgcn_mfma_f32_16x16x32_bf16(alo[mt], bh, acc[mt][nt], 0, 0, 0);
            }
        }

        if (more) {
            __syncthreads();
            storeAB();
            __syncthreads();
        }
    }

    const int nb = M >> 9;   // batches (32)
    #pragma unroll
    for (int mt = 0; mt < 2; ++mt)
        #pragma unroll
        for (int nt = 0; nt < 4; ++nt) {
            const int dk = nt * 16 + lrow;
            const int m0 = bm + wm + mt * 16 + quad * 4;
            const int b_ = m0 >> 9, q = m0 & 511;
            if (sel == 2) {
                h4 v;
                #pragma unroll
                for (int reg = 0; reg < 4; ++reg) v[reg] = (_Float16)acc[mt][nt][reg];
                *(h4*)&Vo[(((size_t)head * nb + b_) * DKx + dk) * Nx + q] = v;
            } else {
                __bf16* hp = (sel == 1) ? Khg : Qhg;
                __bf16* lp = (sel == 1) ? Klg : Qlg;
                #pragma unroll
                for (int reg = 0; reg < 4; ++reg) {
                    float v = acc[mt][nt][reg];
                    __bf16 hi = (__bf16)v;
                    size_t oidx = (((size_t)head * nb + b_) * Nx + (q + reg)) * DKx + dk;
                    hp[oidx] = hi;
                    lp[oidx] = (__bf16)(v - (float)hi);
                }
            }
        }
}

// ---------------------------------------------------------------------------
// MFMA flash attention: Q,K bf16 hi/lo planes [H,B,N,DK]; V fp16 [H,B,DK,N].
// Q frags in registers; single K/V LDS buffer + register prefetch;
// wave-parallel softmax. Output: heads bf16 hi/lo planes [TOK][D].
// ---------------------------------------------------------------------------
__global__ __launch_bounds__(256, 4) void attn_kernel(
    const __bf16* __restrict__ Qhg, const __bf16* __restrict__ Qlg,
    const __bf16* __restrict__ Khg, const __bf16* __restrict__ Klg,
    const _Float16* __restrict__ Vtg,
    __bf16* __restrict__ headsH, __bf16* __restrict__ headsL)
{
    __shared__ __align__(16) __bf16    Kh[64][72], Kl[64][72];
    __shared__ __align__(16) _Float16  Vt[64][72];
    __shared__ __align__(16) _Float16  Sp[64][72];
    __shared__ float ml[64], ll[64], al[64];

    const int tid = threadIdx.x;
    const int q0 = blockIdx.x * 64;
    const int hb = blockIdx.y;                 // h*Bx + b
    const size_t base = (size_t)hb * (Nx * DKx);
    const int lane = tid & 63, wv = tid >> 6;
    const int quad = lane >> 4, lrow = lane & 15;
    const int wm = (wv & 1) * 32, wn = (wv >> 1) * 32;
    const int sr = tid >> 2, sc = (tid & 3) * 16;

    {
        size_t off = base + (size_t)(q0 + sr) * DKx + sc;
        *(bfrag8*)&Kh[sr][sc]     = *(const bfrag8*)(Qhg + off);
        *(bfrag8*)&Kh[sr][sc + 8] = *(const bfrag8*)(Qhg + off + 8);
        *(bfrag8*)&Kl[sr][sc]     = *(const bfrag8*)(Qlg + off);
        *(bfrag8*)&Kl[sr][sc + 8] = *(const bfrag8*)(Qlg + off + 8);
    }
    if (tid < 64) { ml[tid] = -INFINITY; ll[tid] = 0.f; }
    __syncthreads();

    bfrag8 qh[2][2], qlo[2][2];
    #pragma unroll
    for (int mt = 0; mt < 2; ++mt)
        #pragma unroll
        for (int ks = 0; ks < 2; ++ks) {
            qh[mt][ks]  = *(const bfrag8*)&Kh[wm + mt * 16 + lrow][ks * 32 + quad * 8];
            qlo[mt][ks] = *(const bfrag8*)&Kl[wm + mt * 16 + lrow][ks * 32 + quad * 8];
        }
    __syncthreads();

    bfrag8 pkh[2], pkl[2];
    hfrag8 pv[2];
    auto loadKV = [&](int n0) {
        size_t off = base + (size_t)(n0 + sr) * DKx + sc;
        pkh[0] = *(const bfrag8*)(Khg + off);
        pkh[1] = *(const bfrag8*)(Khg + off + 8);
        pkl[0] = *(const bfrag8*)(Klg + off);
        pkl[1] = *(const bfrag8*)(Klg + off + 8);
        const _Float16* vp = Vtg + base + (size_t)sr * Nx + n0 + sc;
        pv[0] = *(const hfrag8*)vp;
        pv[1] = *(const hfrag8*)(vp + 8);
    };
    auto storeKV = [&]() {
        *(bfrag8*)&Kh[sr][sc]     = pkh[0];
        *(bfrag8*)&Kh[sr][sc + 8] = pkh[1];
        *(bfrag8*)&Kl[sr][sc]     = pkl[0];
        *(bfrag8*)&Kl[sr][sc + 8] = pkl[1];
        *(hfrag8*)&Vt[sr][sc]     = pv[0];
        *(hfrag8*)&Vt[sr][sc + 8] = pv[1];
    };

    f32x4 accO[2][2] = {};

    loadKV(0); storeKV();
    __syncthreads();

    for (int n0 = 0; n0 < Nx; n0 += 64) {
        const bool more = (n0 + 64 < Nx);
        if (more) loadKV(n0 + 64);

        f32x4 accS[2][2] = {};
        #pragma unroll
        for (int ks = 0; ks < 2; ++ks) {
            bfrag8 bh[2], blo[2];
            #pragma unroll
            for (int nt = 0; nt < 2; ++nt) {
                bh[nt]  = *(const bfrag8*)&Kh[wn + nt * 16 + lrow][ks * 32 + quad * 8];
                blo[nt] = *(const bfrag8*)&Kl[wn + nt * 16 + lrow][ks * 32 + quad * 8];
            }
            #pragma unroll
            for (int mt = 0; mt < 2; ++mt)
                #pragma unroll
                for (int nt = 0; nt < 2; ++nt) {
                    accS[mt][nt] = __builtin_amdgcn_mfma_f32_16x16x32_bf16(qh[mt][ks],  bh[nt],  accS[mt][nt], 0, 0, 0);
                    accS[mt][nt] = __builtin_amdgcn_mfma_f32_16x16x32_bf16(qh[mt][ks],  blo[nt], accS[mt][nt], 0, 0, 0);
                    accS[mt][nt] = __builtin_amdgcn_mfma_f32_16x16x32_bf16(qlo[mt][ks], bh[nt],  accS[mt][nt], 0, 0, 0);
                }
        }
        #pragma unroll
        for (int mt = 0; mt < 2; ++mt)
            #pragma unroll
            for (int nt = 0; nt < 2; ++nt)
                #pragma unroll
                for (int reg = 0; reg < 4; ++reg)
                    Sp[wm + mt * 16 + quad * 4 + reg][wn + nt * 16 + lrow] =
                        (_Float16)(accS[mt][nt][reg] * 0.125f);
        __syncthreads();

        {
            hfrag8 s0 = *(const hfrag8*)&Sp[sr][sc];
            hfrag8 s1 = *(const hfrag8*)&Sp[sr][sc + 8];
            float rmax = -INFINITY;
            #pragma unroll
            for (int j = 0; j < 8; ++j) {
                rmax = fmaxf(rmax, (float)s0[j]);
                rmax = fmaxf(rmax, (float)s1[j]);
            }
            rmax = fmaxf(rmax, __shfl_xor(rmax, 1));
            rmax = fmaxf(rmax, __shfl_xor(rmax, 2));
            float mold = ml[sr];
            float mnew = fmaxf(mold, rmax);
            float sum = 0.f;
            hfrag8 p0, p1;
            #pragma unroll
            for (int j = 0; j < 8; ++j) {
                float pa = __expf((float)s0[j] - mnew);
                float pb = __expf((float)s1[j] - mnew);
                sum += pa + pb;
                p0[j] = (_Float16)pa;
                p1[j] = (_Float16)pb;
            }
            sum += __shfl_xor(sum, 1);
            sum += __shfl_xor(sum, 2);
            *(hfrag8*)&Sp[sr][sc]     = p0;
            *(hfrag8*)&Sp[sr][sc + 8] = p1;
            if ((tid & 3) == 0) {
                float alpha = __expf(mold - mnew);
                ml[sr] = mnew;
                ll[sr] = ll[sr] * alpha + sum;
                al[sr] = alpha;
            }
        }
        __syncthreads();

        #pragma unroll
        for (int mt = 0; mt < 2; ++mt) {
            float a0 = al[wm + mt * 16 + quad * 4 + 0];
            float a1 = al[wm + mt * 16 + quad * 4 + 1];
            float a2 = al[wm + mt * 16 + quad * 4 + 2];
            float a3 = al[wm + mt * 16 + quad * 4 + 3];
            #pragma unroll
            for (int nt = 0; nt < 2; ++nt) {
                accO[mt][nt][0] *= a0; accO[mt][nt][1] *= a1;
                accO[mt][nt][2] *= a2; accO[mt][nt][3] *= a3;
            }
        }
        #pragma unroll
        for (int ks = 0; ks < 2; ++ks) {
            hfrag8 ap[2], bv[2];
            #pragma unroll
            for (int mt = 0; mt < 2; ++mt)
                ap[mt] = *(const hfrag8*)&Sp[wm + mt * 16 + lrow][ks * 32 + quad * 8];
            #pragma unroll
            for (int nt = 0; nt < 2; ++nt)
                bv[nt] = *(const hfrag8*)&Vt[wn + nt * 16 + lrow][ks * 32 + quad * 8];
            #pragma unroll
            for (int mt = 0; mt < 2; ++mt)
                #pragma unroll
                for (int nt = 0; nt < 2; ++nt)
                    accO[mt][nt] = __builtin_amdgcn_mfma_f32_16x16x32_f16(ap[mt], bv[nt], accO[mt][nt], 0, 0, 0);
        }

        if (more) {
            __syncthreads();
            storeKV();
            __syncthreads();
        }
    }

    const int h_ = hb >> 5, b_ = hb & 31;
    #pragma unroll
    for (int mt = 0; mt < 2; ++mt)
        #pragma unroll
        for (int reg = 0; reg < 4; ++reg) {
            int qrow = wm + mt * 16 + quad * 4 + reg;
            float invl = 1.f / ll[qrow];
            size_t tok = (size_t)b_ * Nx + (q0 + qrow);
            #pragma unroll
            for (int nt = 0; nt < 2; ++nt) {
                int dk = wn + nt * 16 + lrow;
                float v = accO[mt][nt][reg] * invl;
                __bf16 hi = (__bf16)v;
                size_t oidx = tok * Dx + h_ * DKx + dk;
                headsH[oidx] = hi;
                headsL[oidx] = (__bf16)(v - (float)hi);
            }
        }
}

// ---------------------------------------------------------------------------
__global__ __launch_bounds__(256) void bn_stats(const float* __restrict__ t, float* __restrict__ stats)
{
    int r0 = blockIdx.x * 16;
    int c = threadIdx.x;
    float s0 = 0, q0 = 0, s1 = 0, q1 = 0;
    for (int r = 0; r < 16; ++r) {
        const float* row = t + (size_t)(r0 + r) * Dx;
        float v0 = row[c], v1 = row[c + 256];
        s0 += v0; q0 += v0 * v0; s1 += v1; q1 += v1 * v1;
    }
    atomicAdd(&stats[c], s0);
    atomicAdd(&stats[c + 256], s1);
    atomicAdd(&stats[Dx + c], q0);
    atomicAdd(&stats[Dx + c + 256], q1);
}

__global__ __launch_bounds__(256) void bn_norm(
    const float* __restrict__ t, const float* __restrict__ stats,
    const void* __restrict__ g32, const void* __restrict__ g16,
    const void* __restrict__ b32, const void* __restrict__ b16,
    __bf16* __restrict__ hh, __bf16* __restrict__ hl, const int* __restrict__ dtp)
{
    const int f32 = *dtp;
    size_t idx = (size_t)blockIdx.x * 256 + threadIdx.x;
    int c = idx & (Dx - 1);
    const float invM = 1.f / (float)TOK;
    float mu = stats[c] * invM;
    float var = stats[Dx + c] * invM - mu * mu;
    float v = (t[idx] - mu) * rsqrtf(var + EPSx) * ldsel(g32, g16, c, f32) + ldsel(b32, b16, c, f32);
    bf2 s = split2(v);
    hh[idx] = s.hi; hl[idx] = s.lo;
}

// ---------------------------------------------------------------------------
__global__ __launch_bounds__(256) void out_h_kernel(
    const __bf16* __restrict__ hh, const __bf16* __restrict__ hl, float* __restrict__ out)
{
    size_t idx = (size_t)blockIdx.x * 256 + threadIdx.x;
    out[idx] = (float)hh[idx] + (float)hl[idx];
}

__global__ __launch_bounds__(512) void out_mean_kernel(
    const __bf16* __restrict__ hh, const __bf16* __restrict__ hl, float* __restrict__ out2)
{
    int b = blockIdx.x;
    int d = threadIdx.x;
    float s = 0.f;
    for (int n = 0; n < Nx; ++n) {
        size_t idx = ((size_t)b * Nx + n) * Dx + d;
        s += (float)hh[idx] + (float)hl[idx];
    }
    out2[b * Dx + d] = s * (1.f / (float)Nx);
}

// ---------------------------------------------------------------------------
extern "C" void kernel_launch(void* const* d_in, const int* in_sizes, int n_in,
                              void* d_out, int out_size, void* d_ws, size_t ws_size,
                              hipStream_t stream)
{
    const void* x   = d_in[0];
    const void* We  = d_in[1];
    const void* be  = d_in[2];
    const void* Wq  = d_in[3];
    const void* Wk  = d_in[4];
    const void* Wv  = d_in[5];
    const void* Wo  = d_in[6];
    const void* g1  = d_in[7];
    const void* b1  = d_in[8];
    const void* W1  = d_in[9];
    const void* bb1 = d_in[10];
    const void* W2  = d_in[11];
    const void* bb2 = d_in[12];
    const void* g2  = d_in[13];
    const void* b2  = d_in[14];

    const size_t szHD = (size_t)TOK * Dx;            // 8,388,608
    const size_t QKN  = (size_t)Hx * Bx * Nx * DKx;  // 8,388,608
    const size_t szQT = (size_t)3 * Hx * DKx * Dx;   // per q/k/v array, all layers: 786,432
    const size_t szW1 = (size_t)3 * FFx * Dx;        // 3,145,728
    const size_t szWqkvL = (size_t)Hx * Dx * DKx;    // per-layer input stride 262,144
    const size_t szWoL   = (size_t)Hx * DKx * Dx;    // 262,144

    // workspace layout:
    // t fp32 (33.5MB) | stats | dtp | hh,hl bf16 (33.5MB) | region (117.4MB) | weight planes (37.7MB)
    float* t     = (float*)d_ws;
    float* stats = t + szHD;
    int*   dtp   = (int*)(stats + 2 * Dx);
    __bf16* hh   = (__bf16*)(stats + 2 * Dx + 64);
    __bf16* hl   = hh + szHD;
    __bf16* region = hl + szHD;

    // attn-phase views inside region
    __bf16*   headsH = region;
    __bf16*   headsL = headsH + szHD;
    __bf16*   Qhg    = headsL + szHD;
    __bf16*   Qlg    = Qhg + QKN;
    __bf16*   Khg    = Qlg + QKN;
    __bf16*   Klg    = Khg + QKN;
    _Float16* Vtg    = (_Float16*)(Klg + QKN);
    // FF-phase view: ffbuf bf16 [TOK, FFx] = 67MB, overlaps headsH..Qlg
    __bf16* ffbuf = region;

    // weight planes (persistent, all layers)
    __bf16* WqTh = (__bf16*)(Vtg + QKN);
    __bf16* WqTl = WqTh + szQT;
    __bf16* WkTh = WqTl + szQT;
    __bf16* WkTl = WkTh + szQT;
    __bf16* WvTh = WkTl + szQT;
    __bf16* WvTl = WvTh + szQT;
    __bf16* WoTh = WvTl + szQT;
    __bf16* WoTl = WoTh + szQT;
    __bf16* W1h  = WoTl + szQT;
    __bf16* W1l  = W1h + szW1;
    __bf16* W2h  = W1l + szW1;
    __bf16* W2l  = W2h + szW1;

    auto p32 = [](const void* p, size_t e) { return (const void*)((const float*)p + e); };
    auto p16 = [](const void* p, size_t e) { return (const void*)((const __hip_bfloat16*)p + e); };

    detect_kernel<<<1, 64, 0, stream>>>(x, dtp);

    // one-time weight conversion (pre-split + pre-transpose)
    transpose_split_kernel<<<dim3(1, 8, 24), 256, 0, stream>>>(Wq, WqTh, WqTl, Dx, DKx, dtp);
    transpose_split_kernel<<<dim3(1, 8, 24), 256, 0, stream>>>(Wk, WkTh, WkTl, Dx, DKx, dtp);
    transpose_split_kernel<<<dim3(1, 8, 24), 256, 0, stream>>>(Wv, WvTh, WvTl, Dx, DKx, dtp);
    transpose_split_kernel<<<dim3(8, 8, 3), 256, 0, stream>>>(Wo, WoTh, WoTl, Dx, Dx, dtp);
    split_kernel<<<szW1 / 256, 256, 0, stream>>>(W1, W1h, W1l, dtp);
    split_kernel<<<szW1 / 256, 256, 0, stream>>>(W2, W2h, W2l, dtp);

    embed_kernel<<<TOK * Dx / 256, 256, 0, stream>>>(x, We, be, hh, hl, dtp);

    const dim3 gQKV(24, TOK / 128);
    const dim3 gWo(Dx / 64, TOK / 128);
    const dim3 gAttn(Nx / 64, Hx * Bx);
    const dim3 gFF1(FFx / 64, TOK / 128);
    const dim3 gFF2(Dx / 64, TOK / 128);
    for (int l = 0; l < 3; ++l) {
        const size_t eQ = (size_t)l * szWqkvL;   // 262,144 per layer (QT arrays)
        const size_t e1 = (size_t)l * FFx * Dx;
        const size_t eD = (size_t)l * Dx, eF = (size_t)l * FFx;

        qkv_mfma<<<gQKV, 256, 0, stream>>>(
            hh, hl,
            WqTh + eQ, WqTl + eQ, WkTh + eQ, WkTl + eQ, WvTh + eQ, WvTl + eQ,
            Qhg, Qlg, Khg, Klg, Vtg, TOK, Dx);
        attn_kernel<<<gAttn, 256, 0, stream>>>(Qhg, Qlg, Khg, Klg, Vtg, headsH, headsL);

        // output projection + residual: t = (hh+hl) + heads @ Wo^T
        gemm2<2, 2, 0><<<gWo, 256, 0, stream>>>(
            headsH, headsL, WoTh + eQ, WoTl + eQ,
            nullptr, nullptr, hh, hl, t, TOK, Dx, Dx, dtp);

        hipMemsetAsync(stats, 0, 2 * Dx * sizeof(float), stream);
        bn_stats<<<1024, 256, 0, stream>>>(t, stats);
        bn_norm<<<TOK * Dx / 256, 256, 0, stream>>>(
            t, stats, p32(g1, eD), p16(g1, eD), p32(b1, eD), p16(b1, eD), hh, hl, dtp);

        // FF
        gemm2<2, 1, 1><<<gFF1, 256, 0, stream>>>(
            hh, hl, W1h + e1, W1l + e1,
            p32(bb1, eF), p16(bb1, eF), nullptr, nullptr, ffbuf, TOK, FFx, Dx, dtp);
        gemm2<1, 2, 0><<<gFF2, 256, 0, stream>>>(
            ffbuf, nullptr, W2h + e1, W2l + e1,
            p32(bb2, eD), p16(bb2, eD), hh, hl, t, TOK, Dx, FFx, dtp);

        hipMemsetAsync(stats, 0, 2 * Dx * sizeof(float), stream);
        bn_stats<<<1024, 256, 0, stream>>>(t, stats);
        bn_norm<<<TOK * Dx / 256, 256, 0, stream>>>(
            t, stats, p32(g2, eD), p16(g2, eD), p32(b2, eD), p16(b2, eD), hh, hl, dtp);
    }

    out_h_kernel<<<TOK * Dx / 256, 256, 0, stream>>>(hh, hl, (float*)d_out);
    out_mean_kernel<<<Bx, Dx, 0, stream>>>(hh, hl, (float*)d_out + (size_t)TOK * Dx);
}

// Round 3
// 1740.441 us; speedup vs baseline: 1.4884x; 1.1211x over previous
//
#include <hip/hip_runtime.h>
#include <hip/hip_bf16.h>

// Problem constants
#define Bx 32
#define Nx 512
#define Dx 512
#define Hx 8
#define DKx 64
#define FFx 2048
#define TOK (Bx * Nx)          // 16384 tokens
#define EPSx 1e-5f

typedef __bf16 bfrag8 __attribute__((ext_vector_type(8)));
typedef float  f32x4  __attribute__((ext_vector_type(4)));
typedef _Float16 hfrag8 __attribute__((ext_vector_type(8)));
typedef _Float16 h4     __attribute__((ext_vector_type(4)));

struct bf2 { __bf16 hi, lo; };
__device__ __forceinline__ bf2 split2(float v) {
    __bf16 h = (__bf16)v;
    bf2 r; r.hi = h; r.lo = (__bf16)(v - (float)h);
    return r;
}

// ---------------------------------------------------------------------------
__device__ __forceinline__ float ldsel(const void* p32, const void* p16, size_t i, int f32) {
    return f32 ? ((const float*)p32)[i]
               : __bfloat162float(((const __hip_bfloat16*)p16)[i]);
}

__global__ void detect_kernel(const void* __restrict__ x, int* __restrict__ flag)
{
    if (threadIdx.x == 0 && blockIdx.x == 0) {
        const unsigned short* u = (const unsigned short*)x;
        int hits = 0;
        for (int i = 0; i < 256; ++i) {
            int e = (u[i] >> 7) & 0xFF;
            if (e >= 0x86) ++hits;
        }
        *flag = (hits > 8) ? 1 : 0;
    }
}

// ---------------------------------------------------------------------------
// Weight conversion: elementwise split to bf16 hi/lo planes.
__global__ __launch_bounds__(256) void split_kernel(
    const void* __restrict__ W, __bf16* __restrict__ oh, __bf16* __restrict__ ol,
    const int* __restrict__ dtp)
{
    const int f32 = *dtp;
    size_t idx = (size_t)blockIdx.x * 256 + threadIdx.x;
    bf2 s = split2(ldsel(W, W, idx, f32));
    oh[idx] = s.hi; ol[idx] = s.lo;
}

// Weight conversion: transpose [R][C] -> [C][R] per matrix (blockIdx.z), split.
__global__ __launch_bounds__(256) void transpose_split_kernel(
    const void* __restrict__ W, __bf16* __restrict__ oh, __bf16* __restrict__ ol,
    int R, int C, const int* __restrict__ dtp)
{
    const int f32 = *dtp;
    __shared__ float tile[64][65];
    const size_t mbase = (size_t)blockIdx.z * R * C;
    const int c0 = blockIdx.x * 64, r0 = blockIdx.y * 64;
    const int tc = threadIdx.x & 63, tg = threadIdx.x >> 6;
    #pragma unroll
    for (int i = 0; i < 16; ++i) {
        int r = tg * 16 + i;
        tile[r][tc] = ldsel(W, W, mbase + (size_t)(r0 + r) * C + c0 + tc, f32);
    }
    __syncthreads();
    #pragma unroll
    for (int i = 0; i < 16; ++i) {
        int cc = tg * 16 + i;
        bf2 s = split2(tile[tc][cc]);
        size_t o = mbase + (size_t)(c0 + cc) * R + r0 + tc;
        oh[o] = s.hi; ol[o] = s.lo;
    }
}

// ---------------------------------------------------------------------------
__global__ __launch_bounds__(256) void embed_kernel(
    const void* __restrict__ x, const void* __restrict__ We,
    const void* __restrict__ be, __bf16* __restrict__ hh, __bf16* __restrict__ hl,
    const int* __restrict__ dtp)
{
    const int f32 = *dtp;
    size_t idx = (size_t)blockIdx.x * 256 + threadIdx.x;
    int d = idx & (Dx - 1);
    size_t t = idx >> 9;
    float v = ldsel(x, x, t * 2, f32)     * ldsel(We, We, d * 2, f32) +
              ldsel(x, x, t * 2 + 1, f32) * ldsel(We, We, d * 2 + 1, f32) +
              ldsel(be, be, d, f32);
    bf2 s = split2(v);
    hh[idx] = s.hi; hl[idx] = s.lo;
}

// ---------------------------------------------------------------------------
// MFMA GEMM on pre-split bf16 planes. 128x128 tile, BK=32, 2x2 wave grid
// (each wave 64x64 out, acc[4][4]). Single LDS buffer + register prefetch.
// XCD-aware bijective blockIdx swizzle (requires nwg % 8 == 0).
// A: row-major [M][K] planes (ASPLIT=1: hi only, 2 MFMA; ASPLIT=2: 3 MFMA)
// B: k-contiguous [N][K] hi/lo planes.
// EPI: 1 +bias,relu ; 2 +bias(opt)+resid(planes)
// OBF: output bf16 ; else fp32
// ---------------------------------------------------------------------------
template <int ASPLIT, int EPI, int OBF>
__global__ __launch_bounds__(256, 3) void gemm3(
    const __bf16* __restrict__ Ahg, const __bf16* __restrict__ Alg,
    const __bf16* __restrict__ Bhg, const __bf16* __restrict__ Blg,
    const void* __restrict__ bias32, const void* __restrict__ bias16,
    const __bf16* __restrict__ residH, const __bf16* __restrict__ residL,
    void* __restrict__ outp, int M, int N, int K, const int* __restrict__ dtp)
{
    const int f32 = *dtp;
    __shared__ __align__(16) __bf16 Ah[128][40];
    __shared__ __align__(16) __bf16 Al[ASPLIT == 2 ? 128 : 1][ASPLIT == 2 ? 40 : 8];
    __shared__ __align__(16) __bf16 Bh[128][40];
    __shared__ __align__(16) __bf16 Bl[128][40];

    const int tid = threadIdx.x;
    // XCD-aware bijective swizzle: XCD x gets a contiguous tile range.
    const int gx = gridDim.x;
    const int nwg = gx * gridDim.y;
    int flat = blockIdx.y * gx + blockIdx.x;
    flat = (flat & 7) * (nwg >> 3) + (flat >> 3);
    const int bm = (flat / gx) * 128;
    const int bn = (flat % gx) * 128;

    const int lane = tid & 63, wv = tid >> 6;
    const int quad = lane >> 4, lrow = lane & 15;
    const int wm = (wv & 1) * 64, wn = (wv >> 1) * 64;

    f32x4 acc[4][4] = {};
    const int ar = tid >> 1, akq = (tid & 1) * 16;

    bfrag8 pah[2], pal[2], pbh[2], pbl[2];
    auto loadAB = [&](int k0) {
        const __bf16* ap = Ahg + (size_t)(bm + ar) * K + k0 + akq;
        pah[0] = *(const bfrag8*)ap;
        pah[1] = *(const bfrag8*)(ap + 8);
        if constexpr (ASPLIT == 2) {
            const __bf16* alp = Alg + (size_t)(bm + ar) * K + k0 + akq;
            pal[0] = *(const bfrag8*)alp;
            pal[1] = *(const bfrag8*)(alp + 8);
        }
        const __bf16* bp = Bhg + (size_t)(bn + ar) * K + k0 + akq;
        pbh[0] = *(const bfrag8*)bp;
        pbh[1] = *(const bfrag8*)(bp + 8);
        const __bf16* blp = Blg + (size_t)(bn + ar) * K + k0 + akq;
        pbl[0] = *(const bfrag8*)blp;
        pbl[1] = *(const bfrag8*)(blp + 8);
    };
    auto storeAB = [&]() {
        *(bfrag8*)&Ah[ar][akq]     = pah[0];
        *(bfrag8*)&Ah[ar][akq + 8] = pah[1];
        if constexpr (ASPLIT == 2) {
            *(bfrag8*)&Al[ar][akq]     = pal[0];
            *(bfrag8*)&Al[ar][akq + 8] = pal[1];
        }
        *(bfrag8*)&Bh[ar][akq]     = pbh[0];
        *(bfrag8*)&Bh[ar][akq + 8] = pbh[1];
        *(bfrag8*)&Bl[ar][akq]     = pbl[0];
        *(bfrag8*)&Bl[ar][akq + 8] = pbl[1];
    };

    loadAB(0); storeAB();
    __syncthreads();

    for (int k0 = 0; k0 < K; k0 += 32) {
        const bool more = (k0 + 32 < K);
        if (more) loadAB(k0 + 32);

        bfrag8 ah[4], alo[4];
        #pragma unroll
        for (int mt = 0; mt < 4; ++mt) {
            ah[mt] = *(const bfrag8*)&Ah[wm + mt * 16 + lrow][quad * 8];
            if constexpr (ASPLIT == 2) alo[mt] = *(const bfrag8*)&Al[wm + mt * 16 + lrow][quad * 8];
        }
        #pragma unroll
        for (int nt = 0; nt < 4; ++nt) {
            bfrag8 bh = *(const bfrag8*)&Bh[wn + nt * 16 + lrow][quad * 8];
            bfrag8 bl = *(const bfrag8*)&Bl[wn + nt * 16 + lrow][quad * 8];
            #pragma unroll
            for (int mt = 0; mt < 4; ++mt) {
                acc[mt][nt] = __builtin_amdgcn_mfma_f32_16x16x32_bf16(ah[mt], bh, acc[mt][nt], 0, 0, 0);
                acc[mt][nt] = __builtin_amdgcn_mfma_f32_16x16x32_bf16(ah[mt], bl, acc[mt][nt], 0, 0, 0);
                if constexpr (ASPLIT == 2)
                    acc[mt][nt] = __builtin_amdgcn_mfma_f32_16x16x32_bf16(alo[mt], bh, acc[mt][nt], 0, 0, 0);
            }
        }

        if (more) {
            __syncthreads();
            storeAB();
            __syncthreads();
        }
    }

    #pragma unroll
    for (int mt = 0; mt < 4; ++mt)
        #pragma unroll
        for (int nt = 0; nt < 4; ++nt)
            #pragma unroll
            for (int reg = 0; reg < 4; ++reg) {
                int m = bm + wm + mt * 16 + quad * 4 + reg;
                int n = bn + wn + nt * 16 + lrow;
                float v = acc[mt][nt][reg];
                if constexpr (EPI == 1) { v += ldsel(bias32, bias16, n, f32); v = fmaxf(v, 0.f); }
                if constexpr (EPI == 2) {
                    if (bias32) v += ldsel(bias32, bias16, n, f32);
                    size_t ridx = (size_t)m * N + n;
                    v += (float)residH[ridx] + (float)residL[ridx];
                }
                if constexpr (OBF) ((__bf16*)outp)[(size_t)m * N + n] = (__bf16)v;
                else               ((float*)outp)[(size_t)m * N + n] = v;
            }
}

// ---------------------------------------------------------------------------
// Fused QKV projection, 128x128 tile version. A = h planes; B = pre-transposed
// split Wq/Wk/Wv planes ([H*DK][D] k-contig per sel). N=1536 grid.x=12.
// Q,K out as bf16 hi/lo planes [H,B,N,DK]; V out fp16 transposed [H,B,DK,N].
// ---------------------------------------------------------------------------
__global__ __launch_bounds__(256, 3) void qkv_mfma(
    const __bf16* __restrict__ Ahg, const __bf16* __restrict__ Alg,
    const __bf16* __restrict__ QTh, const __bf16* __restrict__ QTl,
    const __bf16* __restrict__ KTh, const __bf16* __restrict__ KTl,
    const __bf16* __restrict__ VTh, const __bf16* __restrict__ VTl,
    __bf16* __restrict__ Qhg, __bf16* __restrict__ Qlg,
    __bf16* __restrict__ Khg, __bf16* __restrict__ Klg,
    _Float16* __restrict__ Vo, int M, int K)
{
    __shared__ __align__(16) __bf16 Ah[128][40];
    __shared__ __align__(16) __bf16 Al[128][40];
    __shared__ __align__(16) __bf16 Bh[128][40];
    __shared__ __align__(16) __bf16 Bl[128][40];

    const int tid = threadIdx.x;
    const int gx = gridDim.x;
    const int nwg = gx * gridDim.y;
    int flat = blockIdx.y * gx + blockIdx.x;
    flat = (flat & 7) * (nwg >> 3) + (flat >> 3);
    const int bm = (flat / gx) * 128;
    const int bn = (flat % gx) * 128;          // 0..1536, 128-aligned

    const int sel = bn >> 9;
    const int nloc = bn & 511;                 // row offset within sel's W^T table
    const __bf16* Bhg = ((sel == 0) ? QTh : (sel == 1) ? KTh : VTh) + (size_t)nloc * K;
    const __bf16* Blg = ((sel == 0) ? QTl : (sel == 1) ? KTl : VTl) + (size_t)nloc * K;

    const int lane = tid & 63, wv = tid >> 6;
    const int quad = lane >> 4, lrow = lane & 15;
    const int wm = (wv & 1) * 64, wn = (wv >> 1) * 64;

    f32x4 acc[4][4] = {};
    const int ar = tid >> 1, akq = (tid & 1) * 16;

    bfrag8 pah[2], pal[2], pbh[2], pbl[2];
    auto loadAB = [&](int k0) {
        const __bf16* ap = Ahg + (size_t)(bm + ar) * K + k0 + akq;
        pah[0] = *(const bfrag8*)ap;
        pah[1] = *(const bfrag8*)(ap + 8);
        const __bf16* alp = Alg + (size_t)(bm + ar) * K + k0 + akq;
        pal[0] = *(const bfrag8*)alp;
        pal[1] = *(const bfrag8*)(alp + 8);
        const __bf16* bp = Bhg + (size_t)ar * K + k0 + akq;
        pbh[0] = *(const bfrag8*)bp;
        pbh[1] = *(const bfrag8*)(bp + 8);
        const __bf16* blp = Blg + (size_t)ar * K + k0 + akq;
        pbl[0] = *(const bfrag8*)blp;
        pbl[1] = *(const bfrag8*)(blp + 8);
    };
    auto storeAB = [&]() {
        *(bfrag8*)&Ah[ar][akq]     = pah[0];
        *(bfrag8*)&Ah[ar][akq + 8] = pah[1];
        *(bfrag8*)&Al[ar][akq]     = pal[0];
        *(bfrag8*)&Al[ar][akq + 8] = pal[1];
        *(bfrag8*)&Bh[ar][akq]     = pbh[0];
        *(bfrag8*)&Bh[ar][akq + 8] = pbh[1];
        *(bfrag8*)&Bl[ar][akq]     = pbl[0];
        *(bfrag8*)&Bl[ar][akq + 8] = pbl[1];
    };

    loadAB(0); storeAB();
    __syncthreads();

    for (int k0 = 0; k0 < K; k0 += 32) {
        const bool more = (k0 + 32 < K);
        if (more) loadAB(k0 + 32);

        bfrag8 ah[4], alo[4];
        #pragma unroll
        for (int mt = 0; mt < 4; ++mt) {
            ah[mt]  = *(const bfrag8*)&Ah[wm + mt * 16 + lrow][quad * 8];
            alo[mt] = *(const bfrag8*)&Al[wm + mt * 16 + lrow][quad * 8];
        }
        #pragma unroll
        for (int nt = 0; nt < 4; ++nt) {
            bfrag8 bh = *(const bfrag8*)&Bh[wn + nt * 16 + lrow][quad * 8];
            bfrag8 bl = *(const bfrag8*)&Bl[wn + nt * 16 + lrow][quad * 8];
            #pragma unroll
            for (int mt = 0; mt < 4; ++mt) {
                acc[mt][nt] = __builtin_amdgcn_mfma_f32_16x16x32_bf16(ah[mt],  bh, acc[mt][nt], 0, 0, 0);
                acc[mt][nt] = __builtin_amdgcn_mfma_f32_16x16x32_bf16(ah[mt],  bl, acc[mt][nt], 0, 0, 0);
                acc[mt][nt] = __builtin_amdgcn_mfma_f32_16x16x32_bf16(alo[mt], bh, acc[mt][nt], 0, 0, 0);
            }
        }

        if (more) {
            __syncthreads();
            storeAB();
            __syncthreads();
        }
    }

    const int nb = M >> 9;   // batches (32)
    #pragma unroll
    for (int mt = 0; mt < 4; ++mt)
        #pragma unroll
        for (int nt = 0; nt < 4; ++nt) {
            const int ncol = nloc + wn + nt * 16 + lrow;   // 0..511 within sel
            const int head = ncol >> 6, dk = ncol & 63;
            const int m0 = bm + wm + mt * 16 + quad * 4;
            const int b_ = m0 >> 9, q = m0 & 511;
            if (sel == 2) {
                h4 v;
                #pragma unroll
                for (int reg = 0; reg < 4; ++reg) v[reg] = (_Float16)acc[mt][nt][reg];
                *(h4*)&Vo[(((size_t)head * nb + b_) * DKx + dk) * Nx + q] = v;
            } else {
                __bf16* hp = (sel == 1) ? Khg : Qhg;
                __bf16* lp = (sel == 1) ? Klg : Qlg;
                #pragma unroll
                for (int reg = 0; reg < 4; ++reg) {
                    float v = acc[mt][nt][reg];
                    __bf16 hi = (__bf16)v;
                    size_t oidx = (((size_t)head * nb + b_) * Nx + (q + reg)) * DKx + dk;
                    hp[oidx] = hi;
                    lp[oidx] = (__bf16)(v - (float)hi);
                }
            }
        }
}

// ---------------------------------------------------------------------------
// MFMA flash attention: Q,K bf16 hi/lo planes [H,B,N,DK]; V fp16 [H,B,DK,N].
// Q frags in registers; single K/V LDS buffer + register prefetch;
// wave-parallel softmax. Output: heads bf16 hi/lo planes [TOK][D].
// ---------------------------------------------------------------------------
__global__ __launch_bounds__(256, 4) void attn_kernel(
    const __bf16* __restrict__ Qhg, const __bf16* __restrict__ Qlg,
    const __bf16* __restrict__ Khg, const __bf16* __restrict__ Klg,
    const _Float16* __restrict__ Vtg,
    __bf16* __restrict__ headsH, __bf16* __restrict__ headsL)
{
    __shared__ __align__(16) __bf16    Kh[64][72], Kl[64][72];
    __shared__ __align__(16) _Float16  Vt[64][72];
    __shared__ __align__(16) _Float16  Sp[64][72];
    __shared__ float ml[64], ll[64], al[64];

    const int tid = threadIdx.x;
    const int q0 = blockIdx.x * 64;
    const int hb = blockIdx.y;                 // h*Bx + b
    const size_t base = (size_t)hb * (Nx * DKx);
    const int lane = tid & 63, wv = tid >> 6;
    const int quad = lane >> 4, lrow = lane & 15;
    const int wm = (wv & 1) * 32, wn = (wv >> 1) * 32;
    const int sr = tid >> 2, sc = (tid & 3) * 16;

    {
        size_t off = base + (size_t)(q0 + sr) * DKx + sc;
        *(bfrag8*)&Kh[sr][sc]     = *(const bfrag8*)(Qhg + off);
        *(bfrag8*)&Kh[sr][sc + 8] = *(const bfrag8*)(Qhg + off + 8);
        *(bfrag8*)&Kl[sr][sc]     = *(const bfrag8*)(Qlg + off);
        *(bfrag8*)&Kl[sr][sc + 8] = *(const bfrag8*)(Qlg + off + 8);
    }
    if (tid < 64) { ml[tid] = -INFINITY; ll[tid] = 0.f; }
    __syncthreads();

    bfrag8 qh[2][2], qlo[2][2];
    #pragma unroll
    for (int mt = 0; mt < 2; ++mt)
        #pragma unroll
        for (int ks = 0; ks < 2; ++ks) {
            qh[mt][ks]  = *(const bfrag8*)&Kh[wm + mt * 16 + lrow][ks * 32 + quad * 8];
            qlo[mt][ks] = *(const bfrag8*)&Kl[wm + mt * 16 + lrow][ks * 32 + quad * 8];
        }
    __syncthreads();

    bfrag8 pkh[2], pkl[2];
    hfrag8 pv[2];
    auto loadKV = [&](int n0) {
        size_t off = base + (size_t)(n0 + sr) * DKx + sc;
        pkh[0] = *(const bfrag8*)(Khg + off);
        pkh[1] = *(const bfrag8*)(Khg + off + 8);
        pkl[0] = *(const bfrag8*)(Klg + off);
        pkl[1] = *(const bfrag8*)(Klg + off + 8);
        const _Float16* vp = Vtg + base + (size_t)sr * Nx + n0 + sc;
        pv[0] = *(const hfrag8*)vp;
        pv[1] = *(const hfrag8*)(vp + 8);
    };
    auto storeKV = [&]() {
        *(bfrag8*)&Kh[sr][sc]     = pkh[0];
        *(bfrag8*)&Kh[sr][sc + 8] = pkh[1];
        *(bfrag8*)&Kl[sr][sc]     = pkl[0];
        *(bfrag8*)&Kl[sr][sc + 8] = pkl[1];
        *(hfrag8*)&Vt[sr][sc]     = pv[0];
        *(hfrag8*)&Vt[sr][sc + 8] = pv[1];
    };

    f32x4 accO[2][2] = {};

    loadKV(0); storeKV();
    __syncthreads();

    for (int n0 = 0; n0 < Nx; n0 += 64) {
        const bool more = (n0 + 64 < Nx);
        if (more) loadKV(n0 + 64);

        f32x4 accS[2][2] = {};
        #pragma unroll
        for (int ks = 0; ks < 2; ++ks) {
            bfrag8 bh[2], blo[2];
            #pragma unroll
            for (int nt = 0; nt < 2; ++nt) {
                bh[nt]  = *(const bfrag8*)&Kh[wn + nt * 16 + lrow][ks * 32 + quad * 8];
                blo[nt] = *(const bfrag8*)&Kl[wn + nt * 16 + lrow][ks * 32 + quad * 8];
            }
            #pragma unroll
            for (int mt = 0; mt < 2; ++mt)
                #pragma unroll
                for (int nt = 0; nt < 2; ++nt) {
                    accS[mt][nt] = __builtin_amdgcn_mfma_f32_16x16x32_bf16(qh[mt][ks],  bh[nt],  accS[mt][nt], 0, 0, 0);
                    accS[mt][nt] = __builtin_amdgcn_mfma_f32_16x16x32_bf16(qh[mt][ks],  blo[nt], accS[mt][nt], 0, 0, 0);
                    accS[mt][nt] = __builtin_amdgcn_mfma_f32_16x16x32_bf16(qlo[mt][ks], bh[nt],  accS[mt][nt], 0, 0, 0);
                }
        }
        #pragma unroll
        for (int mt = 0; mt < 2; ++mt)
            #pragma unroll
            for (int nt = 0; nt < 2; ++nt)
                #pragma unroll
                for (int reg = 0; reg < 4; ++reg)
                    Sp[wm + mt * 16 + quad * 4 + reg][wn + nt * 16 + lrow] =
                        (_Float16)(accS[mt][nt][reg] * 0.125f);
        __syncthreads();

        {
            hfrag8 s0 = *(const hfrag8*)&Sp[sr][sc];
            hfrag8 s1 = *(const hfrag8*)&Sp[sr][sc + 8];
            float rmax = -INFINITY;
            #pragma unroll
            for (int j = 0; j < 8; ++j) {
                rmax = fmaxf(rmax, (float)s0[j]);
                rmax = fmaxf(rmax, (float)s1[j]);
            }
            rmax = fmaxf(rmax, __shfl_xor(rmax, 1));
            rmax = fmaxf(rmax, __shfl_xor(rmax, 2));
            float mold = ml[sr];
            float mnew = fmaxf(mold, rmax);
            float sum = 0.f;
            hfrag8 p0, p1;
            #pragma unroll
            for (int j = 0; j < 8; ++j) {
                float pa = __expf((float)s0[j] - mnew);
                float pb = __expf((float)s1[j] - mnew);
                sum += pa + pb;
                p0[j] = (_Float16)pa;
                p1[j] = (_Float16)pb;
            }
            sum += __shfl_xor(sum, 1);
            sum += __shfl_xor(sum, 2);
            *(hfrag8*)&Sp[sr][sc]     = p0;
            *(hfrag8*)&Sp[sr][sc + 8] = p1;
            if ((tid & 3) == 0) {
                float alpha = __expf(mold - mnew);
                ml[sr] = mnew;
                ll[sr] = ll[sr] * alpha + sum;
                al[sr] = alpha;
            }
        }
        __syncthreads();

        #pragma unroll
        for (int mt = 0; mt < 2; ++mt) {
            float a0 = al[wm + mt * 16 + quad * 4 + 0];
            float a1 = al[wm + mt * 16 + quad * 4 + 1];
            float a2 = al[wm + mt * 16 + quad * 4 + 2];
            float a3 = al[wm + mt * 16 + quad * 4 + 3];
            #pragma unroll
            for (int nt = 0; nt < 2; ++nt) {
                accO[mt][nt][0] *= a0; accO[mt][nt][1] *= a1;
                accO[mt][nt][2] *= a2; accO[mt][nt][3] *= a3;
            }
        }
        #pragma unroll
        for (int ks = 0; ks < 2; ++ks) {
            hfrag8 ap[2], bv[2];
            #pragma unroll
            for (int mt = 0; mt < 2; ++mt)
                ap[mt] = *(const hfrag8*)&Sp[wm + mt * 16 + lrow][ks * 32 + quad * 8];
            #pragma unroll
            for (int nt = 0; nt < 2; ++nt)
                bv[nt] = *(const hfrag8*)&Vt[wn + nt * 16 + lrow][ks * 32 + quad * 8];
            #pragma unroll
            for (int mt = 0; mt < 2; ++mt)
                #pragma unroll
                for (int nt = 0; nt < 2; ++nt)
                    accO[mt][nt] = __builtin_amdgcn_mfma_f32_16x16x32_f16(ap[mt], bv[nt], accO[mt][nt], 0, 0, 0);
        }

        if (more) {
            __syncthreads();
            storeKV();
            __syncthreads();
        }
    }

    const int h_ = hb >> 5, b_ = hb & 31;
    #pragma unroll
    for (int mt = 0; mt < 2; ++mt)
        #pragma unroll
        for (int reg = 0; reg < 4; ++reg) {
            int qrow = wm + mt * 16 + quad * 4 + reg;
            float invl = 1.f / ll[qrow];
            size_t tok = (size_t)b_ * Nx + (q0 + qrow);
            #pragma unroll
            for (int nt = 0; nt < 2; ++nt) {
                int dk = wn + nt * 16 + lrow;
                float v = accO[mt][nt][reg] * invl;
                __bf16 hi = (__bf16)v;
                size_t oidx = tok * Dx + h_ * DKx + dk;
                headsH[oidx] = hi;
                headsL[oidx] = (__bf16)(v - (float)hi);
            }
        }
}

// ---------------------------------------------------------------------------
__global__ __launch_bounds__(256) void bn_stats(const float* __restrict__ t, float* __restrict__ stats)
{
    int r0 = blockIdx.x * 16;
    int c = threadIdx.x;
    float s0 = 0, q0 = 0, s1 = 0, q1 = 0;
    for (int r = 0; r < 16; ++r) {
        const float* row = t + (size_t)(r0 + r) * Dx;
        float v0 = row[c], v1 = row[c + 256];
        s0 += v0; q0 += v0 * v0; s1 += v1; q1 += v1 * v1;
    }
    atomicAdd(&stats[c], s0);
    atomicAdd(&stats[c + 256], s1);
    atomicAdd(&stats[Dx + c], q0);
    atomicAdd(&stats[Dx + c + 256], q1);
}

__global__ __launch_bounds__(256) void bn_norm(
    const float* __restrict__ t, const float* __restrict__ stats,
    const void* __restrict__ g32, const void* __restrict__ g16,
    const void* __restrict__ b32, const void* __restrict__ b16,
    __bf16* __restrict__ hh, __bf16* __restrict__ hl, const int* __restrict__ dtp)
{
    const int f32 = *dtp;
    size_t idx = (size_t)blockIdx.x * 256 + threadIdx.x;
    int c = idx & (Dx - 1);
    const float invM = 1.f / (float)TOK;
    float mu = stats[c] * invM;
    float var = stats[Dx + c] * invM - mu * mu;
    float v = (t[idx] - mu) * rsqrtf(var + EPSx) * ldsel(g32, g16, c, f32) + ldsel(b32, b16, c, f32);
    bf2 s = split2(v);
    hh[idx] = s.hi; hl[idx] = s.lo;
}

// ---------------------------------------------------------------------------
__global__ __launch_bounds__(256) void out_h_kernel(
    const __bf16* __restrict__ hh, const __bf16* __restrict__ hl, float* __restrict__ out)
{
    size_t idx = (size_t)blockIdx.x * 256 + threadIdx.x;
    out[idx] = (float)hh[idx] + (float)hl[idx];
}

__global__ __launch_bounds__(512) void out_mean_kernel(
    const __bf16* __restrict__ hh, const __bf16* __restrict__ hl, float* __restrict__ out2)
{
    int b = blockIdx.x;
    int d = threadIdx.x;
    float s = 0.f;
    for (int n = 0; n < Nx; ++n) {
        size_t idx = ((size_t)b * Nx + n) * Dx + d;
        s += (float)hh[idx] + (float)hl[idx];
    }
    out2[b * Dx + d] = s * (1.f / (float)Nx);
}

// ---------------------------------------------------------------------------
extern "C" void kernel_launch(void* const* d_in, const int* in_sizes, int n_in,
                              void* d_out, int out_size, void* d_ws, size_t ws_size,
                              hipStream_t stream)
{
    const void* x   = d_in[0];
    const void* We  = d_in[1];
    const void* be  = d_in[2];
    const void* Wq  = d_in[3];
    const void* Wk  = d_in[4];
    const void* Wv  = d_in[5];
    const void* Wo  = d_in[6];
    const void* g1  = d_in[7];
    const void* b1  = d_in[8];
    const void* W1  = d_in[9];
    const void* bb1 = d_in[10];
    const void* W2  = d_in[11];
    const void* bb2 = d_in[12];
    const void* g2  = d_in[13];
    const void* b2  = d_in[14];

    const size_t szHD = (size_t)TOK * Dx;            // 8,388,608
    const size_t QKN  = (size_t)Hx * Bx * Nx * DKx;  // 8,388,608
    const size_t szQT = (size_t)3 * Hx * DKx * Dx;   // per q/k/v array, all layers
    const size_t szW1 = (size_t)3 * FFx * Dx;
    const size_t szWqkvL = (size_t)Hx * Dx * DKx;    // per-layer stride 262,144

    // workspace layout:
    // t fp32 | stats | dtp | hh,hl bf16 | region | weight planes
    float* t     = (float*)d_ws;
    float* stats = t + szHD;
    int*   dtp   = (int*)(stats + 2 * Dx);
    __bf16* hh   = (__bf16*)(stats + 2 * Dx + 64);
    __bf16* hl   = hh + szHD;
    __bf16* region = hl + szHD;

    // attn-phase views inside region
    __bf16*   headsH = region;
    __bf16*   headsL = headsH + szHD;
    __bf16*   Qhg    = headsL + szHD;
    __bf16*   Qlg    = Qhg + QKN;
    __bf16*   Khg    = Qlg + QKN;
    __bf16*   Klg    = Khg + QKN;
    _Float16* Vtg    = (_Float16*)(Klg + QKN);
    // FF-phase view: ffbuf bf16 [TOK, FFx], overlaps headsH..Qlg
    __bf16* ffbuf = region;

    // weight planes (persistent, all layers)
    __bf16* WqTh = (__bf16*)(Vtg + QKN);
    __bf16* WqTl = WqTh + szQT;
    __bf16* WkTh = WqTl + szQT;
    __bf16* WkTl = WkTh + szQT;
    __bf16* WvTh = WkTl + szQT;
    __bf16* WvTl = WvTh + szQT;
    __bf16* WoTh = WvTl + szQT;
    __bf16* WoTl = WoTh + szQT;
    __bf16* W1h  = WoTl + szQT;
    __bf16* W1l  = W1h + szW1;
    __bf16* W2h  = W1l + szW1;
    __bf16* W2l  = W2h + szW1;

    auto p32 = [](const void* p, size_t e) { return (const void*)((const float*)p + e); };
    auto p16 = [](const void* p, size_t e) { return (const void*)((const __hip_bfloat16*)p + e); };

    detect_kernel<<<1, 64, 0, stream>>>(x, dtp);

    // one-time weight conversion (pre-split + pre-transpose)
    transpose_split_kernel<<<dim3(1, 8, 24), 256, 0, stream>>>(Wq, WqTh, WqTl, Dx, DKx, dtp);
    transpose_split_kernel<<<dim3(1, 8, 24), 256, 0, stream>>>(Wk, WkTh, WkTl, Dx, DKx, dtp);
    transpose_split_kernel<<<dim3(1, 8, 24), 256, 0, stream>>>(Wv, WvTh, WvTl, Dx, DKx, dtp);
    transpose_split_kernel<<<dim3(8, 8, 3), 256, 0, stream>>>(Wo, WoTh, WoTl, Dx, Dx, dtp);
    split_kernel<<<szW1 / 256, 256, 0, stream>>>(W1, W1h, W1l, dtp);
    split_kernel<<<szW1 / 256, 256, 0, stream>>>(W2, W2h, W2l, dtp);

    embed_kernel<<<TOK * Dx / 256, 256, 0, stream>>>(x, We, be, hh, hl, dtp);

    const dim3 gQKV(12, TOK / 128);                   // 1536 blocks
    const dim3 gWo(Dx / 128, TOK / 128);              // 512 blocks
    const dim3 gAttn(Nx / 64, Hx * Bx);               // 2048 blocks
    const dim3 gFF1(FFx / 128, TOK / 128);            // 2048 blocks
    const dim3 gFF2(Dx / 128, TOK / 128);             // 512 blocks
    for (int l = 0; l < 3; ++l) {
        const size_t eQ = (size_t)l * szWqkvL;
        const size_t e1 = (size_t)l * FFx * Dx;
        const size_t eD = (size_t)l * Dx, eF = (size_t)l * FFx;

        qkv_mfma<<<gQKV, 256, 0, stream>>>(
            hh, hl,
            WqTh + eQ, WqTl + eQ, WkTh + eQ, WkTl + eQ, WvTh + eQ, WvTl + eQ,
            Qhg, Qlg, Khg, Klg, Vtg, TOK, Dx);
        attn_kernel<<<gAttn, 256, 0, stream>>>(Qhg, Qlg, Khg, Klg, Vtg, headsH, headsL);

        // output projection + residual: t = (hh+hl) + heads @ Wo^T
        gemm3<2, 2, 0><<<gWo, 256, 0, stream>>>(
            headsH, headsL, WoTh + eQ, WoTl + eQ,
            nullptr, nullptr, hh, hl, t, TOK, Dx, Dx, dtp);

        hipMemsetAsync(stats, 0, 2 * Dx * sizeof(float), stream);
        bn_stats<<<1024, 256, 0, stream>>>(t, stats);
        bn_norm<<<TOK * Dx / 256, 256, 0, stream>>>(
            t, stats, p32(g1, eD), p16(g1, eD), p32(b1, eD), p16(b1, eD), hh, hl, dtp);

        // FF
        gemm3<2, 1, 1><<<gFF1, 256, 0, stream>>>(
            hh, hl, W1h + e1, W1l + e1,
            p32(bb1, eF), p16(bb1, eF), nullptr, nullptr, ffbuf, TOK, FFx, Dx, dtp);
        gemm3<1, 2, 0><<<gFF2, 256, 0, stream>>>(
            ffbuf, nullptr, W2h + e1, W2l + e1,
            p32(bb2, eD), p16(bb2, eD), hh, hl, t, TOK, Dx, FFx, dtp);

        hipMemsetAsync(stats, 0, 2 * Dx * sizeof(float), stream);
        bn_stats<<<1024, 256, 0, stream>>>(t, stats);
        bn_norm<<<TOK * Dx / 256, 256, 0, stream>>>(
            t, stats, p32(g2, eD), p16(g2, eD), p32(b2, eD), p16(b2, eD), hh, hl, dtp);
    }

    out_h_kernel<<<TOK * Dx / 256, 256, 0, stream>>>(hh, hl, (float*)d_out);
    out_mean_kernel<<<Bx, Dx, 0, stream>>>(hh, hl, (float*)d_out + (size_t)TOK * Dx);
}

// Round 4
// 1671.810 us; speedup vs baseline: 1.5495x; 1.0411x over previous
//
#include <hip/hip_runtime.h>
#include <hip/hip_bf16.h>

// Problem constants
#define Bx 32
#define Nx 512
#define Dx 512
#define Hx 8
#define DKx 64
#define FFx 2048
#define TOK (Bx * Nx)          // 16384 tokens
#define EPSx 1e-5f

typedef __bf16 bfrag8 __attribute__((ext_vector_type(8)));
typedef float  f32x4  __attribute__((ext_vector_type(4)));
typedef _Float16 hfrag8 __attribute__((ext_vector_type(8)));
typedef _Float16 h4     __attribute__((ext_vector_type(4)));

struct bf2 { __bf16 hi, lo; };
__device__ __forceinline__ bf2 split2(float v) {
    __bf16 h = (__bf16)v;
    bf2 r; r.hi = h; r.lo = (__bf16)(v - (float)h);
    return r;
}

// Direct global->LDS DMA, 16B per lane. LDS dest = wave-uniform base + lane*16.
__device__ __forceinline__ void gl16(const void* g, void* l) {
    __builtin_amdgcn_global_load_lds(
        (const __attribute__((address_space(1))) unsigned int*)g,
        (__attribute__((address_space(3))) unsigned int*)l, 16, 0, 0);
}

// Swizzled byte offset within a plane for logical (row, 16B-slot q).
// Physical row = row>>1 (128B, bank-neutral); slot = (((row&1)<<2)|q) ^ (prow&7).
__device__ __forceinline__ int swzoff(int row, int q) {
    int p = row >> 1;
    int sl = ((row & 1) << 2) | q;
    int s = sl ^ (p & 7);
    return p * 128 + s * 16;
}

// ---------------------------------------------------------------------------
__device__ __forceinline__ float ldsel(const void* p32, const void* p16, size_t i, int f32) {
    return f32 ? ((const float*)p32)[i]
               : __bfloat162float(((const __hip_bfloat16*)p16)[i]);
}

__global__ void detect_kernel(const void* __restrict__ x, int* __restrict__ flag)
{
    if (threadIdx.x == 0 && blockIdx.x == 0) {
        const unsigned short* u = (const unsigned short*)x;
        int hits = 0;
        for (int i = 0; i < 256; ++i) {
            int e = (u[i] >> 7) & 0xFF;
            if (e >= 0x86) ++hits;
        }
        *flag = (hits > 8) ? 1 : 0;
    }
}

// ---------------------------------------------------------------------------
// Weight conversion: elementwise split to bf16 hi/lo planes.
__global__ __launch_bounds__(256) void split_kernel(
    const void* __restrict__ W, __bf16* __restrict__ oh, __bf16* __restrict__ ol,
    const int* __restrict__ dtp)
{
    const int f32 = *dtp;
    size_t idx = (size_t)blockIdx.x * 256 + threadIdx.x;
    bf2 s = split2(ldsel(W, W, idx, f32));
    oh[idx] = s.hi; ol[idx] = s.lo;
}

// Weight conversion: transpose [R][C] -> [C][R] per matrix (blockIdx.z), split.
__global__ __launch_bounds__(256) void transpose_split_kernel(
    const void* __restrict__ W, __bf16* __restrict__ oh, __bf16* __restrict__ ol,
    int R, int C, const int* __restrict__ dtp)
{
    const int f32 = *dtp;
    __shared__ float tile[64][65];
    const size_t mbase = (size_t)blockIdx.z * R * C;
    const int c0 = blockIdx.x * 64, r0 = blockIdx.y * 64;
    const int tc = threadIdx.x & 63, tg = threadIdx.x >> 6;
    #pragma unroll
    for (int i = 0; i < 16; ++i) {
        int r = tg * 16 + i;
        tile[r][tc] = ldsel(W, W, mbase + (size_t)(r0 + r) * C + c0 + tc, f32);
    }
    __syncthreads();
    #pragma unroll
    for (int i = 0; i < 16; ++i) {
        int cc = tg * 16 + i;
        bf2 s = split2(tile[tc][cc]);
        size_t o = mbase + (size_t)(c0 + cc) * R + r0 + tc;
        oh[o] = s.hi; ol[o] = s.lo;
    }
}

// ---------------------------------------------------------------------------
__global__ __launch_bounds__(256) void embed_kernel(
    const void* __restrict__ x, const void* __restrict__ We,
    const void* __restrict__ be, __bf16* __restrict__ hh, __bf16* __restrict__ hl,
    const int* __restrict__ dtp)
{
    const int f32 = *dtp;
    size_t idx = (size_t)blockIdx.x * 256 + threadIdx.x;
    int d = idx & (Dx - 1);
    size_t t = idx >> 9;
    float v = ldsel(x, x, t * 2, f32)     * ldsel(We, We, d * 2, f32) +
              ldsel(x, x, t * 2 + 1, f32) * ldsel(We, We, d * 2 + 1, f32) +
              ldsel(be, be, d, f32);
    bf2 s = split2(v);
    hh[idx] = s.hi; hl[idx] = s.lo;
}

// ---------------------------------------------------------------------------
// MFMA GEMM on pre-split bf16 planes. 128x128 tile, BK=32, 2x2 wave grid.
// Double-buffered LDS fed by global_load_lds (16B), ONE barrier per K-step.
// LDS planes 8KB each, XOR-swizzled (linear DMA dest + pre-swizzled global
// source + swizzled ds_read) -> 2-way bank conflicts (free).
// A: row-major [M][K] planes (ASPLIT=1: hi only; ASPLIT=2: hi+lo, 3 MFMA)
// B: k-contiguous [N][K] hi/lo planes.
// EPI: 1 +bias,relu ; 2 +bias(opt)+resid(planes)
// OBF: output bf16 ; else fp32
// ---------------------------------------------------------------------------
template <int ASPLIT, int EPI, int OBF>
__global__ __launch_bounds__(256, ASPLIT == 2 ? 2 : 3) void gemm3(
    const __bf16* __restrict__ Ahg, const __bf16* __restrict__ Alg,
    const __bf16* __restrict__ Bhg, const __bf16* __restrict__ Blg,
    const void* __restrict__ bias32, const void* __restrict__ bias16,
    const __bf16* __restrict__ residH, const __bf16* __restrict__ residL,
    void* __restrict__ outp, int M, int N, int K, const int* __restrict__ dtp)
{
    constexpr int PLANES = (ASPLIT == 2) ? 4 : 3;
    constexpr int BUFB = PLANES * 8192;
    constexpr int BHI = (ASPLIT == 2) ? 16384 : 8192;   // B-hi plane offset
    const int f32 = *dtp;
    __shared__ __align__(16) unsigned char lds[2][BUFB];

    const int tid = threadIdx.x;
    // XCD-aware bijective swizzle (nwg % 8 == 0).
    const int gx = gridDim.x;
    const int nwg = gx * gridDim.y;
    int flat = blockIdx.y * gx + blockIdx.x;
    flat = (flat & 7) * (nwg >> 3) + (flat >> 3);
    const int bm = (flat / gx) * 128;
    const int bn = (flat % gx) * 128;

    const int lane = tid & 63, wv = tid >> 6;
    const int quad = lane >> 4, lrow = lane & 15;
    const int wm = (wv & 1) * 64, wn = (wv >> 1) * 64;

    f32x4 acc[4][4] = {};

    // staging lane-constants (inverse of the read swizzle)
    const int s2 = (lane & 7) ^ (lane >> 3);
    const int rl = 2 * (lane >> 3) + (s2 >> 2);   // row within 16-row chunk
    const int cl = (s2 & 3) * 8;                  // k element offset

    // wave -> plane assignment (wave-uniform)
    const __bf16* wsrc;
    int wrb;
    if constexpr (ASPLIT == 2) {
        wsrc = (wv == 0) ? Ahg : (wv == 1) ? Alg : (wv == 2) ? Bhg : Blg;
        wrb  = (wv < 2) ? bm : bn;
    } else {
        wsrc = (wv == 0) ? Ahg : (wv == 1) ? Bhg : Blg;
        wrb  = (wv == 0) ? bm : bn;
    }
    const int wplane = wv;

    auto stage = [&](int buf, int k0) {
        if (ASPLIT == 2 || wv < 3) {
            const __bf16* s = wsrc + (size_t)(wrb + rl) * K + k0 + cl;
            #pragma unroll
            for (int ch = 0; ch < 8; ++ch)
                gl16(s + (size_t)(ch * 16) * K, &lds[buf][wplane * 8192 + ch * 1024]);
        }
    };

    // precomputed fragment byte offsets (buffer-relative)
    int offA[4], offB[4];
    #pragma unroll
    for (int mt = 0; mt < 4; ++mt) offA[mt] = swzoff(wm + mt * 16 + lrow, quad);
    #pragma unroll
    for (int nt = 0; nt < 4; ++nt) offB[nt] = BHI + swzoff(wn + nt * 16 + lrow, quad);

    stage(0, 0);
    __syncthreads();

    int cur = 0;
    for (int k0 = 0; k0 < K; k0 += 32) {
        if (k0 + 32 < K) stage(cur ^ 1, k0 + 32);

        const unsigned char* bp = lds[cur];
        bfrag8 ah[4], alo[4];
        #pragma unroll
        for (int mt = 0; mt < 4; ++mt) {
            ah[mt] = *(const bfrag8*)(bp + offA[mt]);
            if constexpr (ASPLIT == 2) alo[mt] = *(const bfrag8*)(bp + offA[mt] + 8192);
        }
        #pragma unroll
        for (int nt = 0; nt < 4; ++nt) {
            bfrag8 bh = *(const bfrag8*)(bp + offB[nt]);
            bfrag8 bl = *(const bfrag8*)(bp + offB[nt] + 8192);
            #pragma unroll
            for (int mt = 0; mt < 4; ++mt) {
                acc[mt][nt] = __builtin_amdgcn_mfma_f32_16x16x32_bf16(ah[mt], bh, acc[mt][nt], 0, 0, 0);
                acc[mt][nt] = __builtin_amdgcn_mfma_f32_16x16x32_bf16(ah[mt], bl, acc[mt][nt], 0, 0, 0);
                if constexpr (ASPLIT == 2)
                    acc[mt][nt] = __builtin_amdgcn_mfma_f32_16x16x32_bf16(alo[mt], bh, acc[mt][nt], 0, 0, 0);
            }
        }

        __syncthreads();   // drains my stage DMA (vmcnt) + all waves' reads
        cur ^= 1;
    }

    #pragma unroll
    for (int mt = 0; mt < 4; ++mt)
        #pragma unroll
        for (int nt = 0; nt < 4; ++nt)
            #pragma unroll
            for (int reg = 0; reg < 4; ++reg) {
                int m = bm + wm + mt * 16 + quad * 4 + reg;
                int n = bn + wn + nt * 16 + lrow;
                float v = acc[mt][nt][reg];
                if constexpr (EPI == 1) { v += ldsel(bias32, bias16, n, f32); v = fmaxf(v, 0.f); }
                if constexpr (EPI == 2) {
                    if (bias32) v += ldsel(bias32, bias16, n, f32);
                    size_t ridx = (size_t)m * N + n;
                    v += (float)residH[ridx] + (float)residL[ridx];
                }
                if constexpr (OBF) ((__bf16*)outp)[(size_t)m * N + n] = (__bf16)v;
                else               ((float*)outp)[(size_t)m * N + n] = v;
            }
}

// ---------------------------------------------------------------------------
// Fused QKV projection, same gload_lds double-buffer structure (ASPLIT2).
// B = pre-transposed split Wq/Wk/Wv planes. N=1536 grid.x=12.
// Q,K out as bf16 hi/lo planes [H,B,N,DK]; V out fp16 transposed [H,B,DK,N].
// ---------------------------------------------------------------------------
__global__ __launch_bounds__(256, 2) void qkv_mfma(
    const __bf16* __restrict__ Ahg, const __bf16* __restrict__ Alg,
    const __bf16* __restrict__ QTh, const __bf16* __restrict__ QTl,
    const __bf16* __restrict__ KTh, const __bf16* __restrict__ KTl,
    const __bf16* __restrict__ VTh, const __bf16* __restrict__ VTl,
    __bf16* __restrict__ Qhg, __bf16* __restrict__ Qlg,
    __bf16* __restrict__ Khg, __bf16* __restrict__ Klg,
    _Float16* __restrict__ Vo, int M, int K)
{
    __shared__ __align__(16) unsigned char lds[2][4 * 8192];

    const int tid = threadIdx.x;
    const int gx = gridDim.x;
    const int nwg = gx * gridDim.y;
    int flat = blockIdx.y * gx + blockIdx.x;
    flat = (flat & 7) * (nwg >> 3) + (flat >> 3);
    const int bm = (flat / gx) * 128;
    const int bn = (flat % gx) * 128;          // 0..1536, 128-aligned

    const int sel = bn >> 9;
    const int nloc = bn & 511;
    const __bf16* Bhg = ((sel == 0) ? QTh : (sel == 1) ? KTh : VTh) + (size_t)nloc * K;
    const __bf16* Blg = ((sel == 0) ? QTl : (sel == 1) ? KTl : VTl) + (size_t)nloc * K;

    const int lane = tid & 63, wv = tid >> 6;
    const int quad = lane >> 4, lrow = lane & 15;
    const int wm = (wv & 1) * 64, wn = (wv >> 1) * 64;

    f32x4 acc[4][4] = {};

    const int s2 = (lane & 7) ^ (lane >> 3);
    const int rl = 2 * (lane >> 3) + (s2 >> 2);
    const int cl = (s2 & 3) * 8;

    const __bf16* wsrc = (wv == 0) ? Ahg : (wv == 1) ? Alg : (wv == 2) ? Bhg : Blg;
    const int wrb = (wv < 2) ? bm : 0;

    auto stage = [&](int buf, int k0) {
        const __bf16* s = wsrc + (size_t)(wrb + rl) * K + k0 + cl;
        #pragma unroll
        for (int ch = 0; ch < 8; ++ch)
            gl16(s + (size_t)(ch * 16) * K, &lds[buf][wv * 8192 + ch * 1024]);
    };

    int offA[4], offB[4];
    #pragma unroll
    for (int mt = 0; mt < 4; ++mt) offA[mt] = swzoff(wm + mt * 16 + lrow, quad);
    #pragma unroll
    for (int nt = 0; nt < 4; ++nt) offB[nt] = 16384 + swzoff(wn + nt * 16 + lrow, quad);

    stage(0, 0);
    __syncthreads();

    int cur = 0;
    for (int k0 = 0; k0 < K; k0 += 32) {
        if (k0 + 32 < K) stage(cur ^ 1, k0 + 32);

        const unsigned char* bp = lds[cur];
        bfrag8 ah[4], alo[4];
        #pragma unroll
        for (int mt = 0; mt < 4; ++mt) {
            ah[mt]  = *(const bfrag8*)(bp + offA[mt]);
            alo[mt] = *(const bfrag8*)(bp + offA[mt] + 8192);
        }
        #pragma unroll
        for (int nt = 0; nt < 4; ++nt) {
            bfrag8 bh = *(const bfrag8*)(bp + offB[nt]);
            bfrag8 bl = *(const bfrag8*)(bp + offB[nt] + 8192);
            #pragma unroll
            for (int mt = 0; mt < 4; ++mt) {
                acc[mt][nt] = __builtin_amdgcn_mfma_f32_16x16x32_bf16(ah[mt],  bh, acc[mt][nt], 0, 0, 0);
                acc[mt][nt] = __builtin_amdgcn_mfma_f32_16x16x32_bf16(ah[mt],  bl, acc[mt][nt], 0, 0, 0);
                acc[mt][nt] = __builtin_amdgcn_mfma_f32_16x16x32_bf16(alo[mt], bh, acc[mt][nt], 0, 0, 0);
            }
        }

        __syncthreads();
        cur ^= 1;
    }

    const int nb = M >> 9;   // batches (32)
    #pragma unroll
    for (int mt = 0; mt < 4; ++mt)
        #pragma unroll
        for (int nt = 0; nt < 4; ++nt) {
            const int ncol = nloc + wn + nt * 16 + lrow;   // 0..511 within sel
            const int head = ncol >> 6, dk = ncol & 63;
            const int m0 = bm + wm + mt * 16 + quad * 4;
            const int b_ = m0 >> 9, q = m0 & 511;
            if (sel == 2) {
                h4 v;
                #pragma unroll
                for (int reg = 0; reg < 4; ++reg) v[reg] = (_Float16)acc[mt][nt][reg];
                *(h4*)&Vo[(((size_t)head * nb + b_) * DKx + dk) * Nx + q] = v;
            } else {
                __bf16* hp = (sel == 1) ? Khg : Qhg;
                __bf16* lp = (sel == 1) ? Klg : Qlg;
                #pragma unroll
                for (int reg = 0; reg < 4; ++reg) {
                    float v = acc[mt][nt][reg];
                    __bf16 hi = (__bf16)v;
                    size_t oidx = (((size_t)head * nb + b_) * Nx + (q + reg)) * DKx + dk;
                    hp[oidx] = hi;
                    lp[oidx] = (__bf16)(v - (float)hi);
                }
            }
        }
}

// ---------------------------------------------------------------------------
// MFMA flash attention: Q,K bf16 hi/lo planes [H,B,N,DK]; V fp16 [H,B,DK,N].
// Q frags in registers; single K/V LDS buffer + register prefetch;
// wave-parallel softmax. Output: heads bf16 hi/lo planes [TOK][D].
// ---------------------------------------------------------------------------
__global__ __launch_bounds__(256, 4) void attn_kernel(
    const __bf16* __restrict__ Qhg, const __bf16* __restrict__ Qlg,
    const __bf16* __restrict__ Khg, const __bf16* __restrict__ Klg,
    const _Float16* __restrict__ Vtg,
    __bf16* __restrict__ headsH, __bf16* __restrict__ headsL)
{
    __shared__ __align__(16) __bf16    Kh[64][72], Kl[64][72];
    __shared__ __align__(16) _Float16  Vt[64][72];
    __shared__ __align__(16) _Float16  Sp[64][72];
    __shared__ float ml[64], ll[64], al[64];

    const int tid = threadIdx.x;
    const int q0 = blockIdx.x * 64;
    const int hb = blockIdx.y;                 // h*Bx + b
    const size_t base = (size_t)hb * (Nx * DKx);
    const int lane = tid & 63, wv = tid >> 6;
    const int quad = lane >> 4, lrow = lane & 15;
    const int wm = (wv & 1) * 32, wn = (wv >> 1) * 32;
    const int sr = tid >> 2, sc = (tid & 3) * 16;

    {
        size_t off = base + (size_t)(q0 + sr) * DKx + sc;
        *(bfrag8*)&Kh[sr][sc]     = *(const bfrag8*)(Qhg + off);
        *(bfrag8*)&Kh[sr][sc + 8] = *(const bfrag8*)(Qhg + off + 8);
        *(bfrag8*)&Kl[sr][sc]     = *(const bfrag8*)(Qlg + off);
        *(bfrag8*)&Kl[sr][sc + 8] = *(const bfrag8*)(Qlg + off + 8);
    }
    if (tid < 64) { ml[tid] = -INFINITY; ll[tid] = 0.f; }
    __syncthreads();

    bfrag8 qh[2][2], qlo[2][2];
    #pragma unroll
    for (int mt = 0; mt < 2; ++mt)
        #pragma unroll
        for (int ks = 0; ks < 2; ++ks) {
            qh[mt][ks]  = *(const bfrag8*)&Kh[wm + mt * 16 + lrow][ks * 32 + quad * 8];
            qlo[mt][ks] = *(const bfrag8*)&Kl[wm + mt * 16 + lrow][ks * 32 + quad * 8];
        }
    __syncthreads();

    bfrag8 pkh[2], pkl[2];
    hfrag8 pv[2];
    auto loadKV = [&](int n0) {
        size_t off = base + (size_t)(n0 + sr) * DKx + sc;
        pkh[0] = *(const bfrag8*)(Khg + off);
        pkh[1] = *(const bfrag8*)(Khg + off + 8);
        pkl[0] = *(const bfrag8*)(Klg + off);
        pkl[1] = *(const bfrag8*)(Klg + off + 8);
        const _Float16* vp = Vtg + base + (size_t)sr * Nx + n0 + sc;
        pv[0] = *(const hfrag8*)vp;
        pv[1] = *(const hfrag8*)(vp + 8);
    };
    auto storeKV = [&]() {
        *(bfrag8*)&Kh[sr][sc]     = pkh[0];
        *(bfrag8*)&Kh[sr][sc + 8] = pkh[1];
        *(bfrag8*)&Kl[sr][sc]     = pkl[0];
        *(bfrag8*)&Kl[sr][sc + 8] = pkl[1];
        *(hfrag8*)&Vt[sr][sc]     = pv[0];
        *(hfrag8*)&Vt[sr][sc + 8] = pv[1];
    };

    f32x4 accO[2][2] = {};

    loadKV(0); storeKV();
    __syncthreads();

    for (int n0 = 0; n0 < Nx; n0 += 64) {
        const bool more = (n0 + 64 < Nx);
        if (more) loadKV(n0 + 64);

        f32x4 accS[2][2] = {};
        #pragma unroll
        for (int ks = 0; ks < 2; ++ks) {
            bfrag8 bh[2], blo[2];
            #pragma unroll
            for (int nt = 0; nt < 2; ++nt) {
                bh[nt]  = *(const bfrag8*)&Kh[wn + nt * 16 + lrow][ks * 32 + quad * 8];
                blo[nt] = *(const bfrag8*)&Kl[wn + nt * 16 + lrow][ks * 32 + quad * 8];
            }
            #pragma unroll
            for (int mt = 0; mt < 2; ++mt)
                #pragma unroll
                for (int nt = 0; nt < 2; ++nt) {
                    accS[mt][nt] = __builtin_amdgcn_mfma_f32_16x16x32_bf16(qh[mt][ks],  bh[nt],  accS[mt][nt], 0, 0, 0);
                    accS[mt][nt] = __builtin_amdgcn_mfma_f32_16x16x32_bf16(qh[mt][ks],  blo[nt], accS[mt][nt], 0, 0, 0);
                    accS[mt][nt] = __builtin_amdgcn_mfma_f32_16x16x32_bf16(qlo[mt][ks], bh[nt],  accS[mt][nt], 0, 0, 0);
                }
        }
        #pragma unroll
        for (int mt = 0; mt < 2; ++mt)
            #pragma unroll
            for (int nt = 0; nt < 2; ++nt)
                #pragma unroll
                for (int reg = 0; reg < 4; ++reg)
                    Sp[wm + mt * 16 + quad * 4 + reg][wn + nt * 16 + lrow] =
                        (_Float16)(accS[mt][nt][reg] * 0.125f);
        __syncthreads();

        {
            hfrag8 s0 = *(const hfrag8*)&Sp[sr][sc];
            hfrag8 s1 = *(const hfrag8*)&Sp[sr][sc + 8];
            float rmax = -INFINITY;
            #pragma unroll
            for (int j = 0; j < 8; ++j) {
                rmax = fmaxf(rmax, (float)s0[j]);
                rmax = fmaxf(rmax, (float)s1[j]);
            }
            rmax = fmaxf(rmax, __shfl_xor(rmax, 1));
            rmax = fmaxf(rmax, __shfl_xor(rmax, 2));
            float mold = ml[sr];
            float mnew = fmaxf(mold, rmax);
            float sum = 0.f;
            hfrag8 p0, p1;
            #pragma unroll
            for (int j = 0; j < 8; ++j) {
                float pa = __expf((float)s0[j] - mnew);
                float pb = __expf((float)s1[j] - mnew);
                sum += pa + pb;
                p0[j] = (_Float16)pa;
                p1[j] = (_Float16)pb;
            }
            sum += __shfl_xor(sum, 1);
            sum += __shfl_xor(sum, 2);
            *(hfrag8*)&Sp[sr][sc]     = p0;
            *(hfrag8*)&Sp[sr][sc + 8] = p1;
            if ((tid & 3) == 0) {
                float alpha = __expf(mold - mnew);
                ml[sr] = mnew;
                ll[sr] = ll[sr] * alpha + sum;
                al[sr] = alpha;
            }
        }
        __syncthreads();

        #pragma unroll
        for (int mt = 0; mt < 2; ++mt) {
            float a0 = al[wm + mt * 16 + quad * 4 + 0];
            float a1 = al[wm + mt * 16 + quad * 4 + 1];
            float a2 = al[wm + mt * 16 + quad * 4 + 2];
            float a3 = al[wm + mt * 16 + quad * 4 + 3];
            #pragma unroll
            for (int nt = 0; nt < 2; ++nt) {
                accO[mt][nt][0] *= a0; accO[mt][nt][1] *= a1;
                accO[mt][nt][2] *= a2; accO[mt][nt][3] *= a3;
            }
        }
        #pragma unroll
        for (int ks = 0; ks < 2; ++ks) {
            hfrag8 ap[2], bv[2];
            #pragma unroll
            for (int mt = 0; mt < 2; ++mt)
                ap[mt] = *(const hfrag8*)&Sp[wm + mt * 16 + lrow][ks * 32 + quad * 8];
            #pragma unroll
            for (int nt = 0; nt < 2; ++nt)
                bv[nt] = *(const hfrag8*)&Vt[wn + nt * 16 + lrow][ks * 32 + quad * 8];
            #pragma unroll
            for (int mt = 0; mt < 2; ++mt)
                #pragma unroll
                for (int nt = 0; nt < 2; ++nt)
                    accO[mt][nt] = __builtin_amdgcn_mfma_f32_16x16x32_f16(ap[mt], bv[nt], accO[mt][nt], 0, 0, 0);
        }

        if (more) {
            __syncthreads();
            storeKV();
            __syncthreads();
        }
    }

    const int h_ = hb >> 5, b_ = hb & 31;
    #pragma unroll
    for (int mt = 0; mt < 2; ++mt)
        #pragma unroll
        for (int reg = 0; reg < 4; ++reg) {
            int qrow = wm + mt * 16 + quad * 4 + reg;
            float invl = 1.f / ll[qrow];
            size_t tok = (size_t)b_ * Nx + (q0 + qrow);
            #pragma unroll
            for (int nt = 0; nt < 2; ++nt) {
                int dk = wn + nt * 16 + lrow;
                float v = accO[mt][nt][reg] * invl;
                __bf16 hi = (__bf16)v;
                size_t oidx = tok * Dx + h_ * DKx + dk;
                headsH[oidx] = hi;
                headsL[oidx] = (__bf16)(v - (float)hi);
            }
        }
}

// ---------------------------------------------------------------------------
__global__ __launch_bounds__(256) void bn_stats(const float* __restrict__ t, float* __restrict__ stats)
{
    int r0 = blockIdx.x * 16;
    int c = threadIdx.x;
    float s0 = 0, q0 = 0, s1 = 0, q1 = 0;
    for (int r = 0; r < 16; ++r) {
        const float* row = t + (size_t)(r0 + r) * Dx;
        float v0 = row[c], v1 = row[c + 256];
        s0 += v0; q0 += v0 * v0; s1 += v1; q1 += v1 * v1;
    }
    atomicAdd(&stats[c], s0);
    atomicAdd(&stats[c + 256], s1);
    atomicAdd(&stats[Dx + c], q0);
    atomicAdd(&stats[Dx + c + 256], q1);
}

__global__ __launch_bounds__(256) void bn_norm(
    const float* __restrict__ t, const float* __restrict__ stats,
    const void* __restrict__ g32, const void* __restrict__ g16,
    const void* __restrict__ b32, const void* __restrict__ b16,
    __bf16* __restrict__ hh, __bf16* __restrict__ hl, const int* __restrict__ dtp)
{
    const int f32 = *dtp;
    size_t idx = (size_t)blockIdx.x * 256 + threadIdx.x;
    int c = idx & (Dx - 1);
    const float invM = 1.f / (float)TOK;
    float mu = stats[c] * invM;
    float var = stats[Dx + c] * invM - mu * mu;
    float v = (t[idx] - mu) * rsqrtf(var + EPSx) * ldsel(g32, g16, c, f32) + ldsel(b32, b16, c, f32);
    bf2 s = split2(v);
    hh[idx] = s.hi; hl[idx] = s.lo;
}

// ---------------------------------------------------------------------------
__global__ __launch_bounds__(256) void out_h_kernel(
    const __bf16* __restrict__ hh, const __bf16* __restrict__ hl, float* __restrict__ out)
{
    size_t idx = (size_t)blockIdx.x * 256 + threadIdx.x;
    out[idx] = (float)hh[idx] + (float)hl[idx];
}

__global__ __launch_bounds__(512) void out_mean_kernel(
    const __bf16* __restrict__ hh, const __bf16* __restrict__ hl, float* __restrict__ out2)
{
    int b = blockIdx.x;
    int d = threadIdx.x;
    float s = 0.f;
    for (int n = 0; n < Nx; ++n) {
        size_t idx = ((size_t)b * Nx + n) * Dx + d;
        s += (float)hh[idx] + (float)hl[idx];
    }
    out2[b * Dx + d] = s * (1.f / (float)Nx);
}

// ---------------------------------------------------------------------------
extern "C" void kernel_launch(void* const* d_in, const int* in_sizes, int n_in,
                              void* d_out, int out_size, void* d_ws, size_t ws_size,
                              hipStream_t stream)
{
    const void* x   = d_in[0];
    const void* We  = d_in[1];
    const void* be  = d_in[2];
    const void* Wq  = d_in[3];
    const void* Wk  = d_in[4];
    const void* Wv  = d_in[5];
    const void* Wo  = d_in[6];
    const void* g1  = d_in[7];
    const void* b1  = d_in[8];
    const void* W1  = d_in[9];
    const void* bb1 = d_in[10];
    const void* W2  = d_in[11];
    const void* bb2 = d_in[12];
    const void* g2  = d_in[13];
    const void* b2  = d_in[14];

    const size_t szHD = (size_t)TOK * Dx;            // 8,388,608
    const size_t QKN  = (size_t)Hx * Bx * Nx * DKx;  // 8,388,608
    const size_t szQT = (size_t)3 * Hx * DKx * Dx;   // per q/k/v array, all layers
    const size_t szW1 = (size_t)3 * FFx * Dx;
    const size_t szWqkvL = (size_t)Hx * Dx * DKx;    // per-layer stride 262,144

    // workspace layout:
    // t fp32 | stats | dtp | hh,hl bf16 | region | weight planes
    float* t     = (float*)d_ws;
    float* stats = t + szHD;
    int*   dtp   = (int*)(stats + 2 * Dx);
    __bf16* hh   = (__bf16*)(stats + 2 * Dx + 64);
    __bf16* hl   = hh + szHD;
    __bf16* region = hl + szHD;

    // attn-phase views inside region
    __bf16*   headsH = region;
    __bf16*   headsL = headsH + szHD;
    __bf16*   Qhg    = headsL + szHD;
    __bf16*   Qlg    = Qhg + QKN;
    __bf16*   Khg    = Qlg + QKN;
    __bf16*   Klg    = Khg + QKN;
    _Float16* Vtg    = (_Float16*)(Klg + QKN);
    // FF-phase view: ffbuf bf16 [TOK, FFx], overlaps headsH..Qlg
    __bf16* ffbuf = region;

    // weight planes (persistent, all layers)
    __bf16* WqTh = (__bf16*)(Vtg + QKN);
    __bf16* WqTl = WqTh + szQT;
    __bf16* WkTh = WqTl + szQT;
    __bf16* WkTl = WkTh + szQT;
    __bf16* WvTh = WkTl + szQT;
    __bf16* WvTl = WvTh + szQT;
    __bf16* WoTh = WvTl + szQT;
    __bf16* WoTl = WoTh + szQT;
    __bf16* W1h  = WoTl + szQT;
    __bf16* W1l  = W1h + szW1;
    __bf16* W2h  = W1l + szW1;
    __bf16* W2l  = W2h + szW1;

    auto p32 = [](const void* p, size_t e) { return (const void*)((const float*)p + e); };
    auto p16 = [](const void* p, size_t e) { return (const void*)((const __hip_bfloat16*)p + e); };

    detect_kernel<<<1, 64, 0, stream>>>(x, dtp);

    // one-time weight conversion (pre-split + pre-transpose)
    transpose_split_kernel<<<dim3(1, 8, 24), 256, 0, stream>>>(Wq, WqTh, WqTl, Dx, DKx, dtp);
    transpose_split_kernel<<<dim3(1, 8, 24), 256, 0, stream>>>(Wk, WkTh, WkTl, Dx, DKx, dtp);
    transpose_split_kernel<<<dim3(1, 8, 24), 256, 0, stream>>>(Wv, WvTh, WvTl, Dx, DKx, dtp);
    transpose_split_kernel<<<dim3(8, 8, 3), 256, 0, stream>>>(Wo, WoTh, WoTl, Dx, Dx, dtp);
    split_kernel<<<szW1 / 256, 256, 0, stream>>>(W1, W1h, W1l, dtp);
    split_kernel<<<szW1 / 256, 256, 0, stream>>>(W2, W2h, W2l, dtp);

    embed_kernel<<<TOK * Dx / 256, 256, 0, stream>>>(x, We, be, hh, hl, dtp);

    const dim3 gQKV(12, TOK / 128);                   // 1536 blocks
    const dim3 gWo(Dx / 128, TOK / 128);              // 512 blocks
    const dim3 gAttn(Nx / 64, Hx * Bx);               // 2048 blocks
    const dim3 gFF1(FFx / 128, TOK / 128);            // 2048 blocks
    const dim3 gFF2(Dx / 128, TOK / 128);             // 512 blocks
    for (int l = 0; l < 3; ++l) {
        const size_t eQ = (size_t)l * szWqkvL;
        const size_t e1 = (size_t)l * FFx * Dx;
        const size_t eD = (size_t)l * Dx, eF = (size_t)l * FFx;

        qkv_mfma<<<gQKV, 256, 0, stream>>>(
            hh, hl,
            WqTh + eQ, WqTl + eQ, WkTh + eQ, WkTl + eQ, WvTh + eQ, WvTl + eQ,
            Qhg, Qlg, Khg, Klg, Vtg, TOK, Dx);
        attn_kernel<<<gAttn, 256, 0, stream>>>(Qhg, Qlg, Khg, Klg, Vtg, headsH, headsL);

        // output projection + residual: t = (hh+hl) + heads @ Wo^T
        gemm3<2, 2, 0><<<gWo, 256, 0, stream>>>(
            headsH, headsL, WoTh + eQ, WoTl + eQ,
            nullptr, nullptr, hh, hl, t, TOK, Dx, Dx, dtp);

        hipMemsetAsync(stats, 0, 2 * Dx * sizeof(float), stream);
        bn_stats<<<1024, 256, 0, stream>>>(t, stats);
        bn_norm<<<TOK * Dx / 256, 256, 0, stream>>>(
            t, stats, p32(g1, eD), p16(g1, eD), p32(b1, eD), p16(b1, eD), hh, hl, dtp);

        // FF
        gemm3<2, 1, 1><<<gFF1, 256, 0, stream>>>(
            hh, hl, W1h + e1, W1l + e1,
            p32(bb1, eF), p16(bb1, eF), nullptr, nullptr, ffbuf, TOK, FFx, Dx, dtp);
        gemm3<1, 2, 0><<<gFF2, 256, 0, stream>>>(
            ffbuf, nullptr, W2h + e1, W2l + e1,
            p32(bb2, eD), p16(bb2, eD), hh, hl, t, TOK, Dx, FFx, dtp);

        hipMemsetAsync(stats, 0, 2 * Dx * sizeof(float), stream);
        bn_stats<<<1024, 256, 0, stream>>>(t, stats);
        bn_norm<<<TOK * Dx / 256, 256, 0, stream>>>(
            t, stats, p32(g2, eD), p16(g2, eD), p32(b2, eD), p16(b2, eD), hh, hl, dtp);
    }

    out_h_kernel<<<TOK * Dx / 256, 256, 0, stream>>>(hh, hl, (float*)d_out);
    out_mean_kernel<<<Bx, Dx, 0, stream>>>(hh, hl, (float*)d_out + (size_t)TOK * Dx);
}